// Round 1
// baseline (877.325 us; speedup 1.0000x reference)
//
#include <hip/hip_runtime.h>
#include <hip/hip_bf16.h>

#define C_ 256
#define N_ 4096
#define B_ 4
#define NG_ 32
#define CPG_ 8

typedef __attribute__((ext_vector_type(8))) __bf16 bf16v8;
typedef __attribute__((ext_vector_type(4))) float f32x4;

__device__ __forceinline__ unsigned short f2bf(float f) {
    return __builtin_bit_cast(unsigned short, __float2bfloat16(f));
}
__device__ __forceinline__ float bf2f(unsigned short u) {
    unsigned int x = ((unsigned int)u) << 16;
    return __builtin_bit_cast(float, x);
}
__device__ __forceinline__ bf16v8 ldf(const unsigned short* p) {
    return *reinterpret_cast<const bf16v8*>(p);
}
__device__ __forceinline__ f32x4 mfma_(bf16v8 a, bf16v8 b, f32x4 c) {
    return __builtin_amdgcn_mfma_f32_16x16x32_bf16(a, b, c, 0, 0, 0);
}

// ---------------- 0. weight split fp32 -> bf16 hi/lo ----------------
__global__ __launch_bounds__(256) void split_w_kernel(
    const float* __restrict__ wq, const float* __restrict__ wk,
    const float* __restrict__ wv, const float* __restrict__ wo,
    unsigned short* __restrict__ wqh, unsigned short* __restrict__ wql,
    unsigned short* __restrict__ wkh, unsigned short* __restrict__ wkl,
    unsigned short* __restrict__ wvh, unsigned short* __restrict__ woh)
{
    int idx = blockIdx.x * 256 + threadIdx.x;   // 65536 elements
    float f; unsigned short h;
    f = wq[idx]; h = f2bf(f); wqh[idx] = h; wql[idx] = f2bf(f - bf2f(h));
    f = wk[idx]; h = f2bf(f); wkh[idx] = h; wkl[idx] = f2bf(f - bf2f(h));
    wvh[idx] = f2bf(wv[idx]);
    woh[idx] = f2bf(wo[idx]);
}

// ---------------- 1. GroupNorm -> hn^T [b][n][c] bf16 hi/lo ----------------
__global__ __launch_bounds__(256) void gn_kernel(
    const float* __restrict__ x, const float* __restrict__ gamma,
    const float* __restrict__ beta,
    unsigned short* __restrict__ hnh, unsigned short* __restrict__ hnl)
{
    int b = blockIdx.x >> 5, g = blockIdx.x & 31;
    const float* xp = x + (size_t)(b * C_ + g * CPG_) * N_;
    int tid = threadIdx.x;
    float s = 0.f, s2 = 0.f;
    for (int idx = tid; idx < CPG_ * N_; idx += 256) {
        float v = xp[idx];
        s += v; s2 += v * v;
    }
    #pragma unroll
    for (int off = 32; off > 0; off >>= 1) {
        s  += __shfl_down(s, off);
        s2 += __shfl_down(s2, off);
    }
    __shared__ float rs[4], rs2[4], stat[2];
    if ((tid & 63) == 0) { rs[tid >> 6] = s; rs2[tid >> 6] = s2; }
    __syncthreads();
    if (tid == 0) {
        float S  = rs[0] + rs[1] + rs[2] + rs[3];
        float S2 = rs2[0] + rs2[1] + rs2[2] + rs2[3];
        float mean = S / (float)(CPG_ * N_);
        float var  = S2 / (float)(CPG_ * N_) - mean * mean;
        stat[0] = mean;
        stat[1] = rsqrtf(var + 1e-6f);
    }
    __syncthreads();
    float mean = stat[0], rstd = stat[1];
    float ga[CPG_], be[CPG_];
    #pragma unroll
    for (int cc = 0; cc < CPG_; cc++) {
        ga[cc] = gamma[g * CPG_ + cc] * rstd;
        be[cc] = beta[g * CPG_ + cc];
    }
    for (int i = tid; i < N_; i += 256) {
        union { unsigned short u[8]; uint4 v; } H, L;
        #pragma unroll
        for (int cc = 0; cc < CPG_; cc++) {
            float hn = (xp[(size_t)cc * N_ + i] - mean) * ga[cc] + be[cc];
            unsigned short h = f2bf(hn);
            H.u[cc] = h;
            L.u[cc] = f2bf(hn - bf2f(h));
        }
        size_t o = (size_t)(b * N_ + i) * C_ + g * CPG_;
        *reinterpret_cast<uint4*>(hnh + o) = H.v;
        *reinterpret_cast<uint4*>(hnl + o) = L.v;
    }
}

// ---------------- 2. q/k projection, 3-term split MFMA ----------------
// out[i][o] = sum_c hn[i][c] * w[o][c] + bias[o], written as hi/lo bf16 [b][n][c]
__global__ __launch_bounds__(256) void proj_qk_kernel(
    const unsigned short* __restrict__ hnh, const unsigned short* __restrict__ hnl,
    const unsigned short* __restrict__ wqh, const unsigned short* __restrict__ wql,
    const unsigned short* __restrict__ wkh, const unsigned short* __restrict__ wkl,
    const float* __restrict__ bq, const float* __restrict__ bk,
    unsigned short* __restrict__ q_hi, unsigned short* __restrict__ q_lo,
    unsigned short* __restrict__ k_hi, unsigned short* __restrict__ k_lo)
{
    int it = blockIdx.x, b = blockIdx.y, which = blockIdx.z;
    const unsigned short* wh = which ? wkh : wqh;
    const unsigned short* wl = which ? wkl : wql;
    const float* bias = which ? bk : bq;
    unsigned short* oh = which ? k_hi : q_hi;
    unsigned short* ol = which ? k_lo : q_lo;
    int tid = threadIdx.x, w = tid >> 6, l = tid & 63;
    int l15 = l & 15, lhi = l >> 4;
    int i0 = it * 64 + w * 16;
    size_t arow = (size_t)(b * N_ + i0 + l15) * C_ + lhi * 8;
    bf16v8 ah[8], al[8];
    #pragma unroll
    for (int kk = 0; kk < 8; kk++) {
        ah[kk] = ldf(hnh + arow + kk * 32);
        al[kk] = ldf(hnl + arow + kk * 32);
    }
    for (int oc = 0; oc < 16; oc++) {
        f32x4 acc = {0.f, 0.f, 0.f, 0.f};
        size_t wrow = (size_t)(oc * 16 + l15) * C_ + lhi * 8;
        #pragma unroll
        for (int kk = 0; kk < 8; kk++) {
            bf16v8 bh = ldf(wh + wrow + kk * 32);
            bf16v8 bl = ldf(wl + wrow + kk * 32);
            acc = mfma_(ah[kk], bh, acc);
            acc = mfma_(ah[kk], bl, acc);
            acc = mfma_(al[kk], bh, acc);
        }
        float bia = bias[oc * 16 + l15];
        #pragma unroll
        for (int r = 0; r < 4; r++) {
            int row = i0 + lhi * 4 + r;
            float v = acc[r] + bia;
            unsigned short h = f2bf(v);
            size_t o = (size_t)(b * N_ + row) * C_ + oc * 16 + l15;
            oh[o] = h;
            ol[o] = f2bf(v - bf2f(h));
        }
    }
}

// ---------------- 3. v projection -> v^T [b][c][n] bf16 ----------------
__global__ __launch_bounds__(256) void proj_v_kernel(
    const unsigned short* __restrict__ hnh, const unsigned short* __restrict__ wvh,
    const float* __restrict__ bv, unsigned short* __restrict__ vT)
{
    int it = blockIdx.x, b = blockIdx.y;
    int tid = threadIdx.x, w = tid >> 6, l = tid & 63;
    int l15 = l & 15, lhi = l >> 4;
    int o0 = w * 64, i0 = it * 64;
    f32x4 acc[4][4];
    #pragma unroll
    for (int mc = 0; mc < 4; mc++)
        #pragma unroll
        for (int nc = 0; nc < 4; nc++) acc[mc][nc] = (f32x4){0.f, 0.f, 0.f, 0.f};
    for (int kk = 0; kk < 8; kk++) {
        bf16v8 af[4], bfv[4];
        #pragma unroll
        for (int mc = 0; mc < 4; mc++)
            af[mc] = ldf(wvh + (size_t)(o0 + mc * 16 + l15) * C_ + kk * 32 + lhi * 8);
        #pragma unroll
        for (int nc = 0; nc < 4; nc++)
            bfv[nc] = ldf(hnh + (size_t)(b * N_ + i0 + nc * 16 + l15) * C_ + kk * 32 + lhi * 8);
        #pragma unroll
        for (int mc = 0; mc < 4; mc++)
            #pragma unroll
            for (int nc = 0; nc < 4; nc++)
                acc[mc][nc] = mfma_(af[mc], bfv[nc], acc[mc][nc]);
    }
    #pragma unroll
    for (int mc = 0; mc < 4; mc++) {
        float bia[4];
        #pragma unroll
        for (int r = 0; r < 4; r++) bia[r] = bv[o0 + mc * 16 + lhi * 4 + r];
        #pragma unroll
        for (int nc = 0; nc < 4; nc++)
            #pragma unroll
            for (int r = 0; r < 4; r++) {
                int o = o0 + mc * 16 + lhi * 4 + r;
                int i = i0 + nc * 16 + l15;
                vT[(size_t)(b * C_ + o) * N_ + i] = f2bf(acc[mc][nc][r] + bia[r]);
            }
    }
}

// ---------------- 4. flash attention ----------------
// att[b][i][c] = softmax_j(q[i]·k[j]) @ v  ; q,k split hi/lo (3-term scores)
__global__ __launch_bounds__(256) void flash_kernel(
    const unsigned short* __restrict__ q_hi, const unsigned short* __restrict__ q_lo,
    const unsigned short* __restrict__ k_hi, const unsigned short* __restrict__ k_lo,
    const unsigned short* __restrict__ vT, unsigned short* __restrict__ att)
{
    int it = blockIdx.x, b = blockIdx.y;
    int tid = threadIdx.x, w = tid >> 6, l = tid & 63;
    int l15 = l & 15, lhi = l >> 4;
    int i0 = it * 64 + w * 16;
    __shared__ __align__(16) unsigned short P[4][16][88];   // padded rows: 176B stride

    bf16v8 qh[8], ql[8];
    size_t qrow = (size_t)(b * N_ + i0 + l15) * C_ + lhi * 8;
    #pragma unroll
    for (int kk = 0; kk < 8; kk++) {
        qh[kk] = ldf(q_hi + qrow + kk * 32);
        ql[kk] = ldf(q_lo + qrow + kk * 32);
    }
    f32x4 oacc[16];
    #pragma unroll
    for (int cc = 0; cc < 16; cc++) oacc[cc] = (f32x4){0.f, 0.f, 0.f, 0.f};
    float m[4], lsum[4];
    #pragma unroll
    for (int r = 0; r < 4; r++) { m[r] = -1e30f; lsum[r] = 0.f; }

    for (int jt = 0; jt < N_ / 64; jt++) {
        int j0 = jt * 64;
        f32x4 s[4];
        #pragma unroll
        for (int jc = 0; jc < 4; jc++) {
            f32x4 a = {0.f, 0.f, 0.f, 0.f};
            size_t krow = (size_t)(b * N_ + j0 + jc * 16 + l15) * C_ + lhi * 8;
            #pragma unroll
            for (int kk = 0; kk < 8; kk++) {
                bf16v8 kh = ldf(k_hi + krow + kk * 32);
                bf16v8 kl = ldf(k_lo + krow + kk * 32);
                a = mfma_(qh[kk], kh, a);
                a = mfma_(qh[kk], kl, a);
                a = mfma_(ql[kk], kh, a);
            }
            s[jc] = a;
        }
        // online softmax (row r of this lane-group = i0 + 4*lhi + r)
        float sc[4];
        #pragma unroll
        for (int r = 0; r < 4; r++) {
            float mt = fmaxf(fmaxf(s[0][r], s[1][r]), fmaxf(s[2][r], s[3][r]));
            #pragma unroll
            for (int mask = 1; mask < 16; mask <<= 1)
                mt = fmaxf(mt, __shfl_xor(mt, mask));
            float mn = fmaxf(m[r], mt);
            sc[r] = __expf(m[r] - mn);
            m[r] = mn;
        }
        float p[4][4], rsum[4];
        #pragma unroll
        for (int r = 0; r < 4; r++) rsum[r] = 0.f;
        #pragma unroll
        for (int jc = 0; jc < 4; jc++)
            #pragma unroll
            for (int r = 0; r < 4; r++) {
                p[jc][r] = __expf(s[jc][r] - m[r]);
                rsum[r] += p[jc][r];
            }
        #pragma unroll
        for (int r = 0; r < 4; r++) {
            #pragma unroll
            for (int mask = 1; mask < 16; mask <<= 1)
                rsum[r] += __shfl_xor(rsum[r], mask);
            lsum[r] = lsum[r] * sc[r] + rsum[r];
        }
        #pragma unroll
        for (int cc = 0; cc < 16; cc++) {
            f32x4 t = oacc[cc];
            #pragma unroll
            for (int r = 0; r < 4; r++) t[r] *= sc[r];
            oacc[cc] = t;
        }
        // P (D-frag layout) -> LDS -> A-frag layout
        #pragma unroll
        for (int jc = 0; jc < 4; jc++)
            #pragma unroll
            for (int r = 0; r < 4; r++)
                P[w][lhi * 4 + r][jc * 16 + l15] = f2bf(p[jc][r]);
        bf16v8 pf[2];
        #pragma unroll
        for (int kk2 = 0; kk2 < 2; kk2++)
            pf[kk2] = ldf(&P[w][l15][kk2 * 32 + lhi * 8]);
        // O += P @ V
        #pragma unroll
        for (int cc = 0; cc < 16; cc++) {
            size_t vrow = (size_t)(b * C_ + cc * 16 + l15) * N_ + j0 + lhi * 8;
            bf16v8 v0 = ldf(vT + vrow);
            bf16v8 v1 = ldf(vT + vrow + 32);
            oacc[cc] = mfma_(pf[0], v0, oacc[cc]);
            oacc[cc] = mfma_(pf[1], v1, oacc[cc]);
        }
    }
    #pragma unroll
    for (int cc = 0; cc < 16; cc++)
        #pragma unroll
        for (int r = 0; r < 4; r++) {
            float val = oacc[cc][r] / lsum[r];
            att[(size_t)(b * N_ + i0 + lhi * 4 + r) * C_ + cc * 16 + l15] = f2bf(val);
        }
}

// ---------------- 5. conv_o + bias + residual ----------------
__global__ __launch_bounds__(256) void final_kernel(
    const unsigned short* __restrict__ att, const unsigned short* __restrict__ woh,
    const float* __restrict__ bo, const float* __restrict__ x,
    float* __restrict__ out)
{
    int it = blockIdx.x, b = blockIdx.y;
    int tid = threadIdx.x, w = tid >> 6, l = tid & 63;
    int l15 = l & 15, lhi = l >> 4;
    int o0 = w * 64, i0 = it * 64;
    f32x4 acc[4][4];
    #pragma unroll
    for (int mc = 0; mc < 4; mc++)
        #pragma unroll
        for (int nc = 0; nc < 4; nc++) acc[mc][nc] = (f32x4){0.f, 0.f, 0.f, 0.f};
    for (int kk = 0; kk < 8; kk++) {
        bf16v8 af[4], bfv[4];
        #pragma unroll
        for (int mc = 0; mc < 4; mc++)
            af[mc] = ldf(woh + (size_t)(o0 + mc * 16 + l15) * C_ + kk * 32 + lhi * 8);
        #pragma unroll
        for (int nc = 0; nc < 4; nc++)
            bfv[nc] = ldf(att + (size_t)(b * N_ + i0 + nc * 16 + l15) * C_ + kk * 32 + lhi * 8);
        #pragma unroll
        for (int mc = 0; mc < 4; mc++)
            #pragma unroll
            for (int nc = 0; nc < 4; nc++)
                acc[mc][nc] = mfma_(af[mc], bfv[nc], acc[mc][nc]);
    }
    #pragma unroll
    for (int mc = 0; mc < 4; mc++) {
        float bia[4];
        #pragma unroll
        for (int r = 0; r < 4; r++) bia[r] = bo[o0 + mc * 16 + lhi * 4 + r];
        #pragma unroll
        for (int nc = 0; nc < 4; nc++)
            #pragma unroll
            for (int r = 0; r < 4; r++) {
                int o = o0 + mc * 16 + lhi * 4 + r;
                int i = i0 + nc * 16 + l15;
                size_t idx = (size_t)(b * C_ + o) * N_ + i;
                out[idx] = x[idx] + acc[mc][nc][r] + bia[r];
            }
    }
}

extern "C" void kernel_launch(void* const* d_in, const int* in_sizes, int n_in,
                              void* d_out, int out_size, void* d_ws, size_t ws_size,
                              hipStream_t stream) {
    const float* x  = (const float*)d_in[0];
    const float* gg = (const float*)d_in[1];
    const float* gb = (const float*)d_in[2];
    const float* wq = (const float*)d_in[3];
    const float* bq = (const float*)d_in[4];
    const float* wk = (const float*)d_in[5];
    const float* bk = (const float*)d_in[6];
    const float* wv = (const float*)d_in[7];
    const float* bv = (const float*)d_in[8];
    const float* wo = (const float*)d_in[9];
    const float* bo = (const float*)d_in[10];
    float* out = (float*)d_out;

    char* p = (char*)d_ws;
    const size_t WSZ = (size_t)C_ * C_ * 2;           // 128 KB per weight split
    const size_t HSZ = (size_t)B_ * N_ * C_ * 2;      // 8 MB per activation array
    unsigned short* wqh = (unsigned short*)p; p += WSZ;
    unsigned short* wql = (unsigned short*)p; p += WSZ;
    unsigned short* wkh = (unsigned short*)p; p += WSZ;
    unsigned short* wkl = (unsigned short*)p; p += WSZ;
    unsigned short* wvh = (unsigned short*)p; p += WSZ;
    unsigned short* woh = (unsigned short*)p; p += WSZ;
    unsigned short* hnh = (unsigned short*)p; p += HSZ;
    unsigned short* hnl = (unsigned short*)p; p += HSZ;
    unsigned short* qhi = (unsigned short*)p; p += HSZ;
    unsigned short* qlo = (unsigned short*)p; p += HSZ;
    unsigned short* khi = (unsigned short*)p; p += HSZ;
    unsigned short* klo = (unsigned short*)p; p += HSZ;
    unsigned short* vt  = (unsigned short*)p; p += HSZ;
    unsigned short* att = hnh;   // hn dead after projections; reuse

    split_w_kernel<<<dim3(C_ * C_ / 256), 256, 0, stream>>>(
        wq, wk, wv, wo, wqh, wql, wkh, wkl, wvh, woh);
    gn_kernel<<<dim3(B_ * NG_), 256, 0, stream>>>(x, gg, gb, hnh, hnl);
    proj_qk_kernel<<<dim3(N_ / 64, B_, 2), 256, 0, stream>>>(
        hnh, hnl, wqh, wql, wkh, wkl, bq, bk, qhi, qlo, khi, klo);
    proj_v_kernel<<<dim3(N_ / 64, B_), 256, 0, stream>>>(hnh, wvh, bv, vt);
    flash_kernel<<<dim3(N_ / 64, B_), 256, 0, stream>>>(qhi, qlo, khi, klo, vt, att);
    final_kernel<<<dim3(N_ / 64, B_), 256, 0, stream>>>(att, woh, bo, x, out);
}

// Round 2
// 555.354 us; speedup vs baseline: 1.5798x; 1.5798x over previous
//
#include <hip/hip_runtime.h>
#include <hip/hip_bf16.h>

#define C_ 256
#define N_ 4096
#define B_ 4
#define NG_ 32
#define CPG_ 8

typedef _Float16 f16;
typedef __attribute__((ext_vector_type(8))) _Float16 f16v8;
typedef __attribute__((ext_vector_type(4))) float f32x4;

__device__ __forceinline__ f16v8 ldh(const f16* p) {
    return *reinterpret_cast<const f16v8*>(p);
}
__device__ __forceinline__ f32x4 mfma16(f16v8 a, f16v8 b, f32x4 c) {
    return __builtin_amdgcn_mfma_f32_16x16x32_f16(a, b, c, 0, 0, 0);
}

// ---------------- 0. weights fp32 -> fp16 ----------------
__global__ __launch_bounds__(256) void conv_w_kernel(
    const float* __restrict__ wq, const float* __restrict__ wk,
    const float* __restrict__ wv, const float* __restrict__ wo,
    f16* __restrict__ wq16, f16* __restrict__ wk16,
    f16* __restrict__ wv16, f16* __restrict__ wo16)
{
    int idx = blockIdx.x * 256 + threadIdx.x;   // 65536 elements
    wq16[idx] = (f16)wq[idx];
    wk16[idx] = (f16)wk[idx];
    wv16[idx] = (f16)wv[idx];
    wo16[idx] = (f16)wo[idx];
}

// ---------------- 1. GroupNorm -> hn^T [b][n][c] fp16 ----------------
__global__ __launch_bounds__(256) void gn_kernel(
    const float* __restrict__ x, const float* __restrict__ gamma,
    const float* __restrict__ beta, f16* __restrict__ hn)
{
    int b = blockIdx.x >> 5, g = blockIdx.x & 31;
    const float* xp = x + (size_t)(b * C_ + g * CPG_) * N_;
    int tid = threadIdx.x;
    float s = 0.f, s2 = 0.f;
    for (int idx = tid; idx < CPG_ * N_; idx += 256) {
        float v = xp[idx];
        s += v; s2 += v * v;
    }
    #pragma unroll
    for (int off = 32; off > 0; off >>= 1) {
        s  += __shfl_down(s, off);
        s2 += __shfl_down(s2, off);
    }
    __shared__ float rs[4], rs2[4], stat[2];
    if ((tid & 63) == 0) { rs[tid >> 6] = s; rs2[tid >> 6] = s2; }
    __syncthreads();
    if (tid == 0) {
        float S  = rs[0] + rs[1] + rs[2] + rs[3];
        float S2 = rs2[0] + rs2[1] + rs2[2] + rs2[3];
        float mean = S / (float)(CPG_ * N_);
        float var  = S2 / (float)(CPG_ * N_) - mean * mean;
        stat[0] = mean;
        stat[1] = rsqrtf(var + 1e-6f);
    }
    __syncthreads();
    float mean = stat[0], rstd = stat[1];
    float ga[CPG_], be[CPG_];
    #pragma unroll
    for (int cc = 0; cc < CPG_; cc++) {
        ga[cc] = gamma[g * CPG_ + cc] * rstd;
        be[cc] = beta[g * CPG_ + cc];
    }
    for (int i = tid; i < N_; i += 256) {
        f16v8 H;
        #pragma unroll
        for (int cc = 0; cc < CPG_; cc++)
            H[cc] = (f16)((xp[(size_t)cc * N_ + i] - mean) * ga[cc] + be[cc]);
        *reinterpret_cast<f16v8*>(hn + (size_t)(b * N_ + i) * C_ + g * CPG_) = H;
    }
}

// ---------------- 2. q/k projection (single-term fp16 MFMA) ----------------
__global__ __launch_bounds__(256) void proj_qk_kernel(
    const f16* __restrict__ hn, const f16* __restrict__ wq16,
    const f16* __restrict__ wk16, const float* __restrict__ bq,
    const float* __restrict__ bk, f16* __restrict__ qo, f16* __restrict__ ko)
{
    int it = blockIdx.x, b = blockIdx.y, which = blockIdx.z;
    const f16* wgt = which ? wk16 : wq16;
    const float* bias = which ? bk : bq;
    f16* outp = which ? ko : qo;
    int tid = threadIdx.x, w = tid >> 6, l = tid & 63;
    int l15 = l & 15, lhi = l >> 4;
    int i0 = it * 64 + w * 16;
    size_t arow = (size_t)(b * N_ + i0 + l15) * C_ + lhi * 8;
    f16v8 af[8];
    #pragma unroll
    for (int kk = 0; kk < 8; kk++) af[kk] = ldh(hn + arow + kk * 32);
    for (int oc = 0; oc < 16; oc++) {
        f32x4 acc = {0.f, 0.f, 0.f, 0.f};
        size_t wrow = (size_t)(oc * 16 + l15) * C_ + lhi * 8;
        #pragma unroll
        for (int kk = 0; kk < 8; kk++)
            acc = mfma16(af[kk], ldh(wgt + wrow + kk * 32), acc);
        float bia = bias[oc * 16 + l15];
        #pragma unroll
        for (int r = 0; r < 4; r++)
            outp[(size_t)(b * N_ + i0 + lhi * 4 + r) * C_ + oc * 16 + l15] =
                (f16)(acc[r] + bia);
    }
}

// ---------------- 3. v projection -> v^T [b][c][n] fp16 ----------------
__global__ __launch_bounds__(256) void proj_v_kernel(
    const f16* __restrict__ hn, const f16* __restrict__ wv16,
    const float* __restrict__ bv, f16* __restrict__ vT)
{
    int it = blockIdx.x, b = blockIdx.y;
    int tid = threadIdx.x, w = tid >> 6, l = tid & 63;
    int l15 = l & 15, lhi = l >> 4;
    int o0 = w * 64, i0 = it * 64;
    f32x4 acc[4][4];
    #pragma unroll
    for (int mc = 0; mc < 4; mc++)
        #pragma unroll
        for (int nc = 0; nc < 4; nc++) acc[mc][nc] = (f32x4){0.f, 0.f, 0.f, 0.f};
    for (int kk = 0; kk < 8; kk++) {
        f16v8 af[4], bfv[4];
        #pragma unroll
        for (int mc = 0; mc < 4; mc++)
            af[mc] = ldh(wv16 + (size_t)(o0 + mc * 16 + l15) * C_ + kk * 32 + lhi * 8);
        #pragma unroll
        for (int nc = 0; nc < 4; nc++)
            bfv[nc] = ldh(hn + (size_t)(b * N_ + i0 + nc * 16 + l15) * C_ + kk * 32 + lhi * 8);
        #pragma unroll
        for (int mc = 0; mc < 4; mc++)
            #pragma unroll
            for (int nc = 0; nc < 4; nc++)
                acc[mc][nc] = mfma16(af[mc], bfv[nc], acc[mc][nc]);
    }
    #pragma unroll
    for (int mc = 0; mc < 4; mc++) {
        float bia[4];
        #pragma unroll
        for (int r = 0; r < 4; r++) bia[r] = bv[o0 + mc * 16 + lhi * 4 + r];
        #pragma unroll
        for (int nc = 0; nc < 4; nc++)
            #pragma unroll
            for (int r = 0; r < 4; r++) {
                int o = o0 + mc * 16 + lhi * 4 + r;
                int i = i0 + nc * 16 + l15;
                vT[(size_t)(b * C_ + o) * N_ + i] = (f16)(acc[mc][nc][r] + bia[r]);
            }
    }
}

// ---------------- 4. flash attention (fp16, LDS-staged K, dbuf) ----------------
// K tile [32][256] fp16 in LDS, XOR-swizzled (byte ^= (row&7)<<4) via
// pre-swizzled global SOURCE (linear LDS dest for global_load_lds) + swizzled read.
__device__ __forceinline__ void stage_tile(const f16* kbase, f16* dst, int j0,
                                           int w, int l) {
    #pragma unroll
    for (int rd = 0; rd < 4; rd++) {
        int cb = (rd * 4 + w) * 64;          // wave-uniform chunk base
        int mc = cb + l;                     // this lane's 16B chunk
        int row = mc >> 5;                   // 32 chunks (512B) per row
        int xoff = ((mc & 31) << 4) ^ ((row & 7) << 4);
        const f16* gsrc = kbase + (size_t)(j0 + row) * C_ + (xoff >> 1);
        __builtin_amdgcn_global_load_lds(
            (const __attribute__((address_space(1))) void*)gsrc,
            (__attribute__((address_space(3))) void*)(dst + (size_t)cb * 8),
            16, 0, 0);
    }
}

__global__ __launch_bounds__(256) void flash_kernel(
    const f16* __restrict__ q, const f16* __restrict__ k,
    const f16* __restrict__ vT, f16* __restrict__ att)
{
    int it = blockIdx.x, b = blockIdx.y;
    int tid = threadIdx.x, w = tid >> 6, l = tid & 63;
    int l15 = l & 15, lhi = l >> 4;
    int i0 = it * 64 + w * 16;
    __shared__ __align__(16) f16 kb[2][32][256];   // 2 x 16KB
    __shared__ __align__(16) f16 P[4][16][40];     // padded 80B rows

    const f16* kbase = k + (size_t)b * N_ * C_;

    f16v8 qf[8];
    size_t qrow = (size_t)(b * N_ + i0 + l15) * C_ + lhi * 8;
    #pragma unroll
    for (int kk = 0; kk < 8; kk++) qf[kk] = ldh(q + qrow + kk * 32);

    const f16* vp[16];
    #pragma unroll
    for (int cc = 0; cc < 16; cc++)
        vp[cc] = vT + (size_t)(b * C_ + cc * 16 + l15) * N_ + lhi * 8;

    f32x4 oacc[16];
    #pragma unroll
    for (int cc = 0; cc < 16; cc++) oacc[cc] = (f32x4){0.f, 0.f, 0.f, 0.f};
    float m[4], lsum[4];
    #pragma unroll
    for (int r = 0; r < 4; r++) { m[r] = -1e30f; lsum[r] = 0.f; }

    stage_tile(kbase, &kb[0][0][0], 0, w, l);
    __syncthreads();   // drains vmcnt(0) before barrier

    for (int jt = 0; jt < N_ / 32; jt++) {
        int cur = jt & 1;
        if (jt + 1 < N_ / 32)
            stage_tile(kbase, &kb[cur ^ 1][0][0], (jt + 1) * 32, w, l);

        // ---- QK^T from LDS (swizzled read) ----
        const char* kbc = (const char*)&kb[cur][0][0];
        f32x4 s[2];
        s[0] = (f32x4){0.f, 0.f, 0.f, 0.f};
        s[1] = (f32x4){0.f, 0.f, 0.f, 0.f};
        #pragma unroll
        for (int kk = 0; kk < 8; kk++) {
            #pragma unroll
            for (int jc = 0; jc < 2; jc++) {
                int row = jc * 16 + l15;
                int off = row * 512 + ((kk * 64 + lhi * 16) ^ ((row & 7) << 4));
                f16v8 kf = *reinterpret_cast<const f16v8*>(kbc + off);
                s[jc] = mfma16(qf[kk], kf, s[jc]);
            }
        }

        // ---- online softmax (rows r = i0 + lhi*4 + r) ----
        float sc[4];
        #pragma unroll
        for (int r = 0; r < 4; r++) {
            float mt = fmaxf(s[0][r], s[1][r]);
            #pragma unroll
            for (int mask = 1; mask < 16; mask <<= 1)
                mt = fmaxf(mt, __shfl_xor(mt, mask));
            float mn = fmaxf(m[r], mt);
            sc[r] = __expf(m[r] - mn);
            m[r] = mn;
        }
        float p0[4], p1[4], rsum[4];
        #pragma unroll
        for (int r = 0; r < 4; r++) {
            p0[r] = __expf(s[0][r] - m[r]);
            p1[r] = __expf(s[1][r] - m[r]);
            rsum[r] = p0[r] + p1[r];
            #pragma unroll
            for (int mask = 1; mask < 16; mask <<= 1)
                rsum[r] += __shfl_xor(rsum[r], mask);
            lsum[r] = lsum[r] * sc[r] + rsum[r];
        }
        #pragma unroll
        for (int cc = 0; cc < 16; cc++) {
            #pragma unroll
            for (int r = 0; r < 4; r++) oacc[cc][r] *= sc[r];
        }

        // ---- P (D-frag) -> LDS -> A-frag ----
        #pragma unroll
        for (int r = 0; r < 4; r++) {
            P[w][lhi * 4 + r][l15]      = (f16)p0[r];
            P[w][lhi * 4 + r][16 + l15] = (f16)p1[r];
        }
        f16v8 pf = *reinterpret_cast<const f16v8*>(&P[w][l15][lhi * 8]);

        // ---- O += P @ V (V from global, L2-resident) ----
        int j0 = jt * 32;
        #pragma unroll
        for (int cc = 0; cc < 16; cc++) {
            f16v8 vf = ldh(vp[cc] + j0);
            oacc[cc] = mfma16(pf, vf, oacc[cc]);
        }
        __syncthreads();   // drains prefetch (vmcnt 0) + guards buffer swap
    }

    float inv[4];
    #pragma unroll
    for (int r = 0; r < 4; r++) inv[r] = 1.f / lsum[r];
    #pragma unroll
    for (int cc = 0; cc < 16; cc++)
        #pragma unroll
        for (int r = 0; r < 4; r++)
            att[(size_t)(b * N_ + i0 + lhi * 4 + r) * C_ + cc * 16 + l15] =
                (f16)(oacc[cc][r] * inv[r]);
}

// ---------------- 5. conv_o + bias + residual ----------------
__global__ __launch_bounds__(256) void final_kernel(
    const f16* __restrict__ att, const f16* __restrict__ wo16,
    const float* __restrict__ bo, const float* __restrict__ x,
    float* __restrict__ out)
{
    int it = blockIdx.x, b = blockIdx.y;
    int tid = threadIdx.x, w = tid >> 6, l = tid & 63;
    int l15 = l & 15, lhi = l >> 4;
    int o0 = w * 64, i0 = it * 64;
    f32x4 acc[4][4];
    #pragma unroll
    for (int mc = 0; mc < 4; mc++)
        #pragma unroll
        for (int nc = 0; nc < 4; nc++) acc[mc][nc] = (f32x4){0.f, 0.f, 0.f, 0.f};
    for (int kk = 0; kk < 8; kk++) {
        f16v8 af[4], bfv[4];
        #pragma unroll
        for (int mc = 0; mc < 4; mc++)
            af[mc] = ldh(wo16 + (size_t)(o0 + mc * 16 + l15) * C_ + kk * 32 + lhi * 8);
        #pragma unroll
        for (int nc = 0; nc < 4; nc++)
            bfv[nc] = ldh(att + (size_t)(b * N_ + i0 + nc * 16 + l15) * C_ + kk * 32 + lhi * 8);
        #pragma unroll
        for (int mc = 0; mc < 4; mc++)
            #pragma unroll
            for (int nc = 0; nc < 4; nc++)
                acc[mc][nc] = mfma16(af[mc], bfv[nc], acc[mc][nc]);
    }
    #pragma unroll
    for (int mc = 0; mc < 4; mc++) {
        float bia[4];
        #pragma unroll
        for (int r = 0; r < 4; r++) bia[r] = bo[o0 + mc * 16 + lhi * 4 + r];
        #pragma unroll
        for (int nc = 0; nc < 4; nc++)
            #pragma unroll
            for (int r = 0; r < 4; r++) {
                int o = o0 + mc * 16 + lhi * 4 + r;
                int i = i0 + nc * 16 + l15;
                size_t idx = (size_t)(b * C_ + o) * N_ + i;
                out[idx] = x[idx] + acc[mc][nc][r] + bia[r];
            }
    }
}

extern "C" void kernel_launch(void* const* d_in, const int* in_sizes, int n_in,
                              void* d_out, int out_size, void* d_ws, size_t ws_size,
                              hipStream_t stream) {
    const float* x  = (const float*)d_in[0];
    const float* gg = (const float*)d_in[1];
    const float* gb = (const float*)d_in[2];
    const float* wq = (const float*)d_in[3];
    const float* bq = (const float*)d_in[4];
    const float* wk = (const float*)d_in[5];
    const float* bk = (const float*)d_in[6];
    const float* wv = (const float*)d_in[7];
    const float* bv = (const float*)d_in[8];
    const float* wo = (const float*)d_in[9];
    const float* bo = (const float*)d_in[10];
    float* out = (float*)d_out;

    char* p = (char*)d_ws;
    const size_t WSZ = (size_t)C_ * C_ * 2;       // 128 KB per fp16 weight
    const size_t HSZ = (size_t)B_ * N_ * C_ * 2;  // 8 MB per fp16 activation
    f16* wq16 = (f16*)p; p += WSZ;
    f16* wk16 = (f16*)p; p += WSZ;
    f16* wv16 = (f16*)p; p += WSZ;
    f16* wo16 = (f16*)p; p += WSZ;
    f16* hn   = (f16*)p; p += HSZ;
    f16* qo   = (f16*)p; p += HSZ;
    f16* ko   = (f16*)p; p += HSZ;
    f16* vt   = (f16*)p; p += HSZ;
    f16* att  = hn;   // hn dead after projections; reuse

    conv_w_kernel<<<dim3(C_ * C_ / 256), 256, 0, stream>>>(
        wq, wk, wv, wo, wq16, wk16, wv16, wo16);
    gn_kernel<<<dim3(B_ * NG_), 256, 0, stream>>>(x, gg, gb, hn);
    proj_qk_kernel<<<dim3(N_ / 64, B_, 2), 256, 0, stream>>>(
        hn, wq16, wk16, bq, bk, qo, ko);
    proj_v_kernel<<<dim3(N_ / 64, B_), 256, 0, stream>>>(hn, wv16, bv, vt);
    flash_kernel<<<dim3(N_ / 64, B_), 256, 0, stream>>>(qo, ko, vt, att);
    final_kernel<<<dim3(N_ / 64, B_), 256, 0, stream>>>(att, wo16, bo, x, out);
}

// Round 3
// 538.698 us; speedup vs baseline: 1.6286x; 1.0309x over previous
//
#include <hip/hip_runtime.h>
#include <hip/hip_bf16.h>

#define C_ 256
#define N_ 4096
#define B_ 4
#define NG_ 32
#define CPG_ 8
#define SPLITS 4
#define JT_PER (N_ / 32 / SPLITS)   // 32 j-tiles of 32 per split

typedef _Float16 f16;
typedef __attribute__((ext_vector_type(8))) _Float16 f16v8;
typedef __attribute__((ext_vector_type(4))) float f32x4;

__device__ __forceinline__ f16v8 ldh(const f16* p) {
    return *reinterpret_cast<const f16v8*>(p);
}
__device__ __forceinline__ f32x4 mfma16(f16v8 a, f16v8 b, f32x4 c) {
    return __builtin_amdgcn_mfma_f32_16x16x32_f16(a, b, c, 0, 0, 0);
}

// ---------------- 0. weights fp32 -> fp16 ----------------
__global__ __launch_bounds__(256) void conv_w_kernel(
    const float* __restrict__ wq, const float* __restrict__ wk,
    const float* __restrict__ wv, const float* __restrict__ wo,
    f16* __restrict__ wq16, f16* __restrict__ wk16,
    f16* __restrict__ wv16, f16* __restrict__ wo16)
{
    int idx = blockIdx.x * 256 + threadIdx.x;   // 65536 elements
    wq16[idx] = (f16)wq[idx];
    wk16[idx] = (f16)wk[idx];
    wv16[idx] = (f16)wv[idx];
    wo16[idx] = (f16)wo[idx];
}

// ---------------- 1. GroupNorm -> hn^T [b][n][c] fp16 ----------------
__global__ __launch_bounds__(256) void gn_kernel(
    const float* __restrict__ x, const float* __restrict__ gamma,
    const float* __restrict__ beta, f16* __restrict__ hn)
{
    int b = blockIdx.x >> 5, g = blockIdx.x & 31;
    const float* xp = x + (size_t)(b * C_ + g * CPG_) * N_;
    int tid = threadIdx.x;
    float s = 0.f, s2 = 0.f;
    for (int idx = tid; idx < CPG_ * N_; idx += 256) {
        float v = xp[idx];
        s += v; s2 += v * v;
    }
    #pragma unroll
    for (int off = 32; off > 0; off >>= 1) {
        s  += __shfl_down(s, off);
        s2 += __shfl_down(s2, off);
    }
    __shared__ float rs[4], rs2[4], stat[2];
    if ((tid & 63) == 0) { rs[tid >> 6] = s; rs2[tid >> 6] = s2; }
    __syncthreads();
    if (tid == 0) {
        float S  = rs[0] + rs[1] + rs[2] + rs[3];
        float S2 = rs2[0] + rs2[1] + rs2[2] + rs2[3];
        float mean = S / (float)(CPG_ * N_);
        float var  = S2 / (float)(CPG_ * N_) - mean * mean;
        stat[0] = mean;
        stat[1] = rsqrtf(var + 1e-6f);
    }
    __syncthreads();
    float mean = stat[0], rstd = stat[1];
    float ga[CPG_], be[CPG_];
    #pragma unroll
    for (int cc = 0; cc < CPG_; cc++) {
        ga[cc] = gamma[g * CPG_ + cc] * rstd;
        be[cc] = beta[g * CPG_ + cc];
    }
    for (int i = tid; i < N_; i += 256) {
        f16v8 H;
        #pragma unroll
        for (int cc = 0; cc < CPG_; cc++)
            H[cc] = (f16)((xp[(size_t)cc * N_ + i] - mean) * ga[cc] + be[cc]);
        *reinterpret_cast<f16v8*>(hn + (size_t)(b * N_ + i) * C_ + g * CPG_) = H;
    }
}

// ---------------- 2. q/k projection ----------------
__global__ __launch_bounds__(256) void proj_qk_kernel(
    const f16* __restrict__ hn, const f16* __restrict__ wq16,
    const f16* __restrict__ wk16, const float* __restrict__ bq,
    const float* __restrict__ bk, f16* __restrict__ qo, f16* __restrict__ ko)
{
    int it = blockIdx.x, b = blockIdx.y, which = blockIdx.z;
    const f16* wgt = which ? wk16 : wq16;
    const float* bias = which ? bk : bq;
    f16* outp = which ? ko : qo;
    int tid = threadIdx.x, w = tid >> 6, l = tid & 63;
    int l15 = l & 15, lhi = l >> 4;
    int i0 = it * 64 + w * 16;
    size_t arow = (size_t)(b * N_ + i0 + l15) * C_ + lhi * 8;
    f16v8 af[8];
    #pragma unroll
    for (int kk = 0; kk < 8; kk++) af[kk] = ldh(hn + arow + kk * 32);
    for (int oc = 0; oc < 16; oc++) {
        f32x4 acc = {0.f, 0.f, 0.f, 0.f};
        size_t wrow = (size_t)(oc * 16 + l15) * C_ + lhi * 8;
        #pragma unroll
        for (int kk = 0; kk < 8; kk++)
            acc = mfma16(af[kk], ldh(wgt + wrow + kk * 32), acc);
        float bia = bias[oc * 16 + l15];
        #pragma unroll
        for (int r = 0; r < 4; r++)
            outp[(size_t)(b * N_ + i0 + lhi * 4 + r) * C_ + oc * 16 + l15] =
                (f16)(acc[r] + bia);
    }
}

// ---------------- 3. v projection -> v^T [b][c][n] fp16 ----------------
__global__ __launch_bounds__(256) void proj_v_kernel(
    const f16* __restrict__ hn, const f16* __restrict__ wv16,
    const float* __restrict__ bv, f16* __restrict__ vT)
{
    int it = blockIdx.x, b = blockIdx.y;
    int tid = threadIdx.x, w = tid >> 6, l = tid & 63;
    int l15 = l & 15, lhi = l >> 4;
    int o0 = w * 64, i0 = it * 64;
    f32x4 acc[4][4];
    #pragma unroll
    for (int mc = 0; mc < 4; mc++)
        #pragma unroll
        for (int nc = 0; nc < 4; nc++) acc[mc][nc] = (f32x4){0.f, 0.f, 0.f, 0.f};
    for (int kk = 0; kk < 8; kk++) {
        f16v8 af[4], bfv[4];
        #pragma unroll
        for (int mc = 0; mc < 4; mc++)
            af[mc] = ldh(wv16 + (size_t)(o0 + mc * 16 + l15) * C_ + kk * 32 + lhi * 8);
        #pragma unroll
        for (int nc = 0; nc < 4; nc++)
            bfv[nc] = ldh(hn + (size_t)(b * N_ + i0 + nc * 16 + l15) * C_ + kk * 32 + lhi * 8);
        #pragma unroll
        for (int mc = 0; mc < 4; mc++)
            #pragma unroll
            for (int nc = 0; nc < 4; nc++)
                acc[mc][nc] = mfma16(af[mc], bfv[nc], acc[mc][nc]);
    }
    #pragma unroll
    for (int mc = 0; mc < 4; mc++) {
        float bia[4];
        #pragma unroll
        for (int r = 0; r < 4; r++) bia[r] = bv[o0 + mc * 16 + lhi * 4 + r];
        #pragma unroll
        for (int nc = 0; nc < 4; nc++)
            #pragma unroll
            for (int r = 0; r < 4; r++) {
                int o = o0 + mc * 16 + lhi * 4 + r;
                int i = i0 + nc * 16 + l15;
                vT[(size_t)(b * C_ + o) * N_ + i] = (f16)(acc[mc][nc][r] + bia[r]);
            }
    }
}

// ---------------- 4. flash attention, KV-split ----------------
__device__ __forceinline__ void stage_tile(const f16* kbase, f16* dst, int j0,
                                           int w, int l) {
    #pragma unroll
    for (int rd = 0; rd < 4; rd++) {
        int cb = (rd * 4 + w) * 64;          // wave-uniform chunk base
        int mc = cb + l;                     // this lane's 16B chunk
        int row = mc >> 5;                   // 32 chunks (512B) per row
        int xoff = ((mc & 31) << 4) ^ ((row & 7) << 4);
        const f16* gsrc = kbase + (size_t)(j0 + row) * C_ + (xoff >> 1);
        __builtin_amdgcn_global_load_lds(
            (const __attribute__((address_space(1))) void*)gsrc,
            (__attribute__((address_space(3))) void*)(dst + (size_t)cb * 8),
            16, 0, 0);
    }
}

__global__ __launch_bounds__(256, 4) void flash_split_kernel(
    const f16* __restrict__ q, const f16* __restrict__ k,
    const f16* __restrict__ vT,
    f16* __restrict__ o0p, f16* __restrict__ o1p,
    f16* __restrict__ o2p, f16* __restrict__ o3p,
    float2* __restrict__ stats)
{
    int it = blockIdx.x, b = blockIdx.y, split = blockIdx.z;
    int tid = threadIdx.x, w = tid >> 6, l = tid & 63;
    int l15 = l & 15, lhi = l >> 4;
    int i0 = it * 64 + w * 16;
    int jt0 = split * JT_PER;
    __shared__ __align__(16) f16 kb[2][32][256];   // 2 x 16KB
    __shared__ __align__(16) f16 P[4][16][40];     // padded 80B rows

    const f16* kbase = k + (size_t)b * N_ * C_;
    const f16* vb = vT + (size_t)b * C_ * N_ + (size_t)l15 * N_ + lhi * 8;

    f16v8 qf[8];
    size_t qrow = (size_t)(b * N_ + i0 + l15) * C_ + lhi * 8;
    #pragma unroll
    for (int kk = 0; kk < 8; kk++) qf[kk] = ldh(q + qrow + kk * 32);

    f32x4 oacc[16];
    #pragma unroll
    for (int cc = 0; cc < 16; cc++) oacc[cc] = (f32x4){0.f, 0.f, 0.f, 0.f};
    float m[4], lsum[4];
    #pragma unroll
    for (int r = 0; r < 4; r++) { m[r] = -1e30f; lsum[r] = 0.f; }

    stage_tile(kbase, &kb[0][0][0], jt0 * 32, w, l);
    __syncthreads();

    for (int jt = 0; jt < JT_PER; jt++) {
        int cur = jt & 1;
        if (jt + 1 < JT_PER)
            stage_tile(kbase, &kb[cur ^ 1][0][0], (jt0 + jt + 1) * 32, w, l);

        // ---- QK^T from LDS (swizzled read) ----
        const char* kbc = (const char*)&kb[cur][0][0];
        f32x4 s[2];
        s[0] = (f32x4){0.f, 0.f, 0.f, 0.f};
        s[1] = (f32x4){0.f, 0.f, 0.f, 0.f};
        #pragma unroll
        for (int kk = 0; kk < 8; kk++) {
            #pragma unroll
            for (int jc = 0; jc < 2; jc++) {
                int row = jc * 16 + l15;
                int off = row * 512 + ((kk * 64 + lhi * 16) ^ ((row & 7) << 4));
                f16v8 kf = *reinterpret_cast<const f16v8*>(kbc + off);
                s[jc] = mfma16(qf[kk], kf, s[jc]);
            }
        }

        // ---- online softmax (rows = i0 + lhi*4 + r) ----
        float sc[4];
        #pragma unroll
        for (int r = 0; r < 4; r++) {
            float mt = fmaxf(s[0][r], s[1][r]);
            #pragma unroll
            for (int mask = 1; mask < 16; mask <<= 1)
                mt = fmaxf(mt, __shfl_xor(mt, mask));
            float mn = fmaxf(m[r], mt);
            sc[r] = __expf(m[r] - mn);
            m[r] = mn;
        }
        float p0[4], p1[4], rsum[4];
        #pragma unroll
        for (int r = 0; r < 4; r++) {
            p0[r] = __expf(s[0][r] - m[r]);
            p1[r] = __expf(s[1][r] - m[r]);
            rsum[r] = p0[r] + p1[r];
            #pragma unroll
            for (int mask = 1; mask < 16; mask <<= 1)
                rsum[r] += __shfl_xor(rsum[r], mask);
            lsum[r] = lsum[r] * sc[r] + rsum[r];
        }
        #pragma unroll
        for (int cc = 0; cc < 16; cc++) {
            #pragma unroll
            for (int r = 0; r < 4; r++) oacc[cc][r] *= sc[r];
        }

        // ---- P (D-frag) -> LDS -> A-frag ----
        #pragma unroll
        for (int r = 0; r < 4; r++) {
            P[w][lhi * 4 + r][l15]      = (f16)p0[r];
            P[w][lhi * 4 + r][16 + l15] = (f16)p1[r];
        }
        f16v8 pf = *reinterpret_cast<const f16v8*>(&P[w][l15][lhi * 8]);

        // ---- O += P @ V ----
        int j0 = (jt0 + jt) * 32;
        #pragma unroll
        for (int cc = 0; cc < 16; cc++) {
            f16v8 vf = ldh(vb + (size_t)cc * 16 * N_ + j0);
            oacc[cc] = mfma16(pf, vf, oacc[cc]);
        }
        __syncthreads();
    }

    f16* op = (split == 0) ? o0p : (split == 1) ? o1p : (split == 2) ? o2p : o3p;
    float inv[4];
    #pragma unroll
    for (int r = 0; r < 4; r++) inv[r] = 1.f / lsum[r];
    #pragma unroll
    for (int cc = 0; cc < 16; cc++)
        #pragma unroll
        for (int r = 0; r < 4; r++)
            op[(size_t)(b * N_ + i0 + lhi * 4 + r) * C_ + cc * 16 + l15] =
                (f16)(oacc[cc][r] * inv[r]);
    if (l15 == 0) {
        #pragma unroll
        for (int r = 0; r < 4; r++)
            stats[((size_t)split * B_ + b) * N_ + i0 + lhi * 4 + r] =
                make_float2(m[r], lsum[r]);
    }
}

// ---------------- 4b. combine partials ----------------
__global__ __launch_bounds__(256) void combine_kernel(
    const f16* __restrict__ o0p, const f16* __restrict__ o1p,
    const f16* __restrict__ o2p, const f16* __restrict__ o3p,
    const float2* __restrict__ stats, f16* __restrict__ att)
{
    int it = blockIdx.x, b = blockIdx.y;
    int tid = threadIdx.x;
    int row = it * 64 + (tid >> 2);
    int c0 = (tid & 3) * 64;
    const f16* ops[SPLITS] = {o0p, o1p, o2p, o3p};
    float2 st[SPLITS];
    float M = -1e30f;
    #pragma unroll
    for (int s = 0; s < SPLITS; s++) {
        st[s] = stats[((size_t)s * B_ + b) * N_ + row];
        M = fmaxf(M, st[s].x);
    }
    float wgt[SPLITS], L = 0.f;
    #pragma unroll
    for (int s = 0; s < SPLITS; s++) {
        wgt[s] = st[s].y * __expf(st[s].x - M);
        L += wgt[s];
    }
    float inv = 1.f / L;
    #pragma unroll
    for (int s = 0; s < SPLITS; s++) wgt[s] *= inv;
    size_t base = (size_t)(b * N_ + row) * C_ + c0;
    #pragma unroll
    for (int u = 0; u < 8; u++) {
        float a[8];
        #pragma unroll
        for (int e = 0; e < 8; e++) a[e] = 0.f;
        #pragma unroll
        for (int s = 0; s < SPLITS; s++) {
            f16v8 v = ldh(ops[s] + base + u * 8);
            #pragma unroll
            for (int e = 0; e < 8; e++) a[e] += wgt[s] * (float)v[e];
        }
        f16v8 o;
        #pragma unroll
        for (int e = 0; e < 8; e++) o[e] = (f16)a[e];
        *reinterpret_cast<f16v8*>(att + base + u * 8) = o;
    }
}

// ---------------- 5. conv_o + bias + residual ----------------
__global__ __launch_bounds__(256) void final_kernel(
    const f16* __restrict__ att, const f16* __restrict__ wo16,
    const float* __restrict__ bo, const float* __restrict__ x,
    float* __restrict__ out)
{
    int it = blockIdx.x, b = blockIdx.y;
    int tid = threadIdx.x, w = tid >> 6, l = tid & 63;
    int l15 = l & 15, lhi = l >> 4;
    int o0 = w * 64, i0 = it * 64;
    f32x4 acc[4][4];
    #pragma unroll
    for (int mc = 0; mc < 4; mc++)
        #pragma unroll
        for (int nc = 0; nc < 4; nc++) acc[mc][nc] = (f32x4){0.f, 0.f, 0.f, 0.f};
    for (int kk = 0; kk < 8; kk++) {
        f16v8 af[4], bfv[4];
        #pragma unroll
        for (int mc = 0; mc < 4; mc++)
            af[mc] = ldh(wo16 + (size_t)(o0 + mc * 16 + l15) * C_ + kk * 32 + lhi * 8);
        #pragma unroll
        for (int nc = 0; nc < 4; nc++)
            bfv[nc] = ldh(att + (size_t)(b * N_ + i0 + nc * 16 + l15) * C_ + kk * 32 + lhi * 8);
        #pragma unroll
        for (int mc = 0; mc < 4; mc++)
            #pragma unroll
            for (int nc = 0; nc < 4; nc++)
                acc[mc][nc] = mfma16(af[mc], bfv[nc], acc[mc][nc]);
    }
    #pragma unroll
    for (int mc = 0; mc < 4; mc++) {
        float bia[4];
        #pragma unroll
        for (int r = 0; r < 4; r++) bia[r] = bo[o0 + mc * 16 + lhi * 4 + r];
        #pragma unroll
        for (int nc = 0; nc < 4; nc++)
            #pragma unroll
            for (int r = 0; r < 4; r++) {
                int o = o0 + mc * 16 + lhi * 4 + r;
                int i = i0 + nc * 16 + l15;
                size_t idx = (size_t)(b * C_ + o) * N_ + i;
                out[idx] = x[idx] + acc[mc][nc][r] + bia[r];
            }
    }
}

extern "C" void kernel_launch(void* const* d_in, const int* in_sizes, int n_in,
                              void* d_out, int out_size, void* d_ws, size_t ws_size,
                              hipStream_t stream) {
    const float* x  = (const float*)d_in[0];
    const float* gg = (const float*)d_in[1];
    const float* gb = (const float*)d_in[2];
    const float* wq = (const float*)d_in[3];
    const float* bq = (const float*)d_in[4];
    const float* wk = (const float*)d_in[5];
    const float* bk = (const float*)d_in[6];
    const float* wv = (const float*)d_in[7];
    const float* bv = (const float*)d_in[8];
    const float* wo = (const float*)d_in[9];
    const float* bo = (const float*)d_in[10];
    float* out = (float*)d_out;

    char* p = (char*)d_ws;
    const size_t WSZ = (size_t)C_ * C_ * 2;       // 128 KB per fp16 weight
    const size_t HSZ = (size_t)B_ * N_ * C_ * 2;  // 8 MB per fp16 activation
    f16* wq16 = (f16*)p; p += WSZ;
    f16* wk16 = (f16*)p; p += WSZ;
    f16* wv16 = (f16*)p; p += WSZ;
    f16* wo16 = (f16*)p; p += WSZ;
    f16* hn   = (f16*)p; p += HSZ;
    f16* qo   = (f16*)p; p += HSZ;
    f16* ko   = (f16*)p; p += HSZ;
    f16* vt   = (f16*)p; p += HSZ;
    f16* oex  = (f16*)p; p += 3 * HSZ;            // partials for splits 1..3
    float2* stats = (float2*)p; p += (size_t)SPLITS * B_ * N_ * sizeof(float2);

    f16* o0p = hn;            // hn dead after projections; split-0 partial
    f16* o1p = oex;
    f16* o2p = oex + HSZ / 2;       // HSZ bytes = HSZ/2 f16 elements... careful
    f16* o3p = oex + HSZ;           // (see note below)
    // NOTE: HSZ is in BYTES; oex is f16*. Elements per partial = HSZ/2.
    o2p = oex + (HSZ / 2);
    o3p = oex + (HSZ / 2) * 2;
    f16* att  = qo;           // qo dead after flash; combined output

    conv_w_kernel<<<dim3(C_ * C_ / 256), 256, 0, stream>>>(
        wq, wk, wv, wo, wq16, wk16, wv16, wo16);
    gn_kernel<<<dim3(B_ * NG_), 256, 0, stream>>>(x, gg, gb, hn);
    proj_qk_kernel<<<dim3(N_ / 64, B_, 2), 256, 0, stream>>>(
        hn, wq16, wk16, bq, bk, qo, ko);
    proj_v_kernel<<<dim3(N_ / 64, B_), 256, 0, stream>>>(hn, wv16, bv, vt);
    flash_split_kernel<<<dim3(N_ / 64, B_, SPLITS), 256, 0, stream>>>(
        qo, ko, vt, o0p, o1p, o2p, o3p, stats);
    combine_kernel<<<dim3(N_ / 64, B_), 256, 0, stream>>>(
        o0p, o1p, o2p, o3p, stats, att);
    final_kernel<<<dim3(N_ / 64, B_), 256, 0, stream>>>(att, wo16, bo, x, out);
}

// Round 4
// 287.524 us; speedup vs baseline: 3.0513x; 1.8736x over previous
//
#include <hip/hip_runtime.h>
#include <hip/hip_bf16.h>

#define C_ 256
#define N_ 4096
#define B_ 4
#define NG_ 32
#define CPG_ 8
#define SPLITS 2
#define JT_PER (N_ / 32 / SPLITS)   // 64 j-tiles of 32 per split

typedef _Float16 f16;
typedef __attribute__((ext_vector_type(8))) _Float16 f16v8;
typedef __attribute__((ext_vector_type(4))) float f32x4;

__device__ __forceinline__ f16v8 ldh(const f16* p) {
    return *reinterpret_cast<const f16v8*>(p);
}
__device__ __forceinline__ f32x4 mfma16(f16v8 a, f16v8 b, f32x4 c) {
    return __builtin_amdgcn_mfma_f32_16x16x32_f16(a, b, c, 0, 0, 0);
}

// ---------------- 0. weights fp32 -> fp16 ----------------
__global__ __launch_bounds__(256) void conv_w_kernel(
    const float* __restrict__ wq, const float* __restrict__ wk,
    const float* __restrict__ wv, const float* __restrict__ wo,
    f16* __restrict__ wq16, f16* __restrict__ wk16,
    f16* __restrict__ wv16, f16* __restrict__ wo16)
{
    int idx = blockIdx.x * 256 + threadIdx.x;   // 65536 elements
    wq16[idx] = (f16)wq[idx];
    wk16[idx] = (f16)wk[idx];
    wv16[idx] = (f16)wv[idx];
    wo16[idx] = (f16)wo[idx];
}

// ---------------- 1. GroupNorm -> hn^T [b][n][c] fp16 ----------------
__global__ __launch_bounds__(256) void gn_kernel(
    const float* __restrict__ x, const float* __restrict__ gamma,
    const float* __restrict__ beta, f16* __restrict__ hn)
{
    int b = blockIdx.x >> 5, g = blockIdx.x & 31;
    const float* xp = x + (size_t)(b * C_ + g * CPG_) * N_;
    int tid = threadIdx.x;
    float s = 0.f, s2 = 0.f;
    for (int idx = tid; idx < CPG_ * N_; idx += 256) {
        float v = xp[idx];
        s += v; s2 += v * v;
    }
    #pragma unroll
    for (int off = 32; off > 0; off >>= 1) {
        s  += __shfl_down(s, off);
        s2 += __shfl_down(s2, off);
    }
    __shared__ float rs[4], rs2[4], stat[2];
    if ((tid & 63) == 0) { rs[tid >> 6] = s; rs2[tid >> 6] = s2; }
    __syncthreads();
    if (tid == 0) {
        float S  = rs[0] + rs[1] + rs[2] + rs[3];
        float S2 = rs2[0] + rs2[1] + rs2[2] + rs2[3];
        float mean = S / (float)(CPG_ * N_);
        float var  = S2 / (float)(CPG_ * N_) - mean * mean;
        stat[0] = mean;
        stat[1] = rsqrtf(var + 1e-6f);
    }
    __syncthreads();
    float mean = stat[0], rstd = stat[1];
    float ga[CPG_], be[CPG_];
    #pragma unroll
    for (int cc = 0; cc < CPG_; cc++) {
        ga[cc] = gamma[g * CPG_ + cc] * rstd;
        be[cc] = beta[g * CPG_ + cc];
    }
    for (int i = tid; i < N_; i += 256) {
        f16v8 H;
        #pragma unroll
        for (int cc = 0; cc < CPG_; cc++)
            H[cc] = (f16)((xp[(size_t)cc * N_ + i] - mean) * ga[cc] + be[cc]);
        *reinterpret_cast<f16v8*>(hn + (size_t)(b * N_ + i) * C_ + g * CPG_) = H;
    }
}

// ---------------- 2. q/k projection ----------------
__global__ __launch_bounds__(256) void proj_qk_kernel(
    const f16* __restrict__ hn, const f16* __restrict__ wq16,
    const f16* __restrict__ wk16, const float* __restrict__ bq,
    const float* __restrict__ bk, f16* __restrict__ qo, f16* __restrict__ ko)
{
    int it = blockIdx.x, b = blockIdx.y, which = blockIdx.z;
    const f16* wgt = which ? wk16 : wq16;
    const float* bias = which ? bk : bq;
    f16* outp = which ? ko : qo;
    int tid = threadIdx.x, w = tid >> 6, l = tid & 63;
    int l15 = l & 15, lhi = l >> 4;
    int i0 = it * 64 + w * 16;
    size_t arow = (size_t)(b * N_ + i0 + l15) * C_ + lhi * 8;
    f16v8 af[8];
    #pragma unroll
    for (int kk = 0; kk < 8; kk++) af[kk] = ldh(hn + arow + kk * 32);
    for (int oc = 0; oc < 16; oc++) {
        f32x4 acc = {0.f, 0.f, 0.f, 0.f};
        size_t wrow = (size_t)(oc * 16 + l15) * C_ + lhi * 8;
        #pragma unroll
        for (int kk = 0; kk < 8; kk++)
            acc = mfma16(af[kk], ldh(wgt + wrow + kk * 32), acc);
        float bia = bias[oc * 16 + l15];
        #pragma unroll
        for (int r = 0; r < 4; r++)
            outp[(size_t)(b * N_ + i0 + lhi * 4 + r) * C_ + oc * 16 + l15] =
                (f16)(acc[r] + bia);
    }
}

// ---------------- 3. v projection -> v^T [b][c][n] fp16 ----------------
__global__ __launch_bounds__(256) void proj_v_kernel(
    const f16* __restrict__ hn, const f16* __restrict__ wv16,
    const float* __restrict__ bv, f16* __restrict__ vT)
{
    int it = blockIdx.x, b = blockIdx.y;
    int tid = threadIdx.x, w = tid >> 6, l = tid & 63;
    int l15 = l & 15, lhi = l >> 4;
    int o0 = w * 64, i0 = it * 64;
    f32x4 acc[4][4];
    #pragma unroll
    for (int mc = 0; mc < 4; mc++)
        #pragma unroll
        for (int nc = 0; nc < 4; nc++) acc[mc][nc] = (f32x4){0.f, 0.f, 0.f, 0.f};
    for (int kk = 0; kk < 8; kk++) {
        f16v8 af[4], bfv[4];
        #pragma unroll
        for (int mc = 0; mc < 4; mc++)
            af[mc] = ldh(wv16 + (size_t)(o0 + mc * 16 + l15) * C_ + kk * 32 + lhi * 8);
        #pragma unroll
        for (int nc = 0; nc < 4; nc++)
            bfv[nc] = ldh(hn + (size_t)(b * N_ + i0 + nc * 16 + l15) * C_ + kk * 32 + lhi * 8);
        #pragma unroll
        for (int mc = 0; mc < 4; mc++)
            #pragma unroll
            for (int nc = 0; nc < 4; nc++)
                acc[mc][nc] = mfma16(af[mc], bfv[nc], acc[mc][nc]);
    }
    #pragma unroll
    for (int mc = 0; mc < 4; mc++) {
        float bia[4];
        #pragma unroll
        for (int r = 0; r < 4; r++) bia[r] = bv[o0 + mc * 16 + lhi * 4 + r];
        #pragma unroll
        for (int nc = 0; nc < 4; nc++)
            #pragma unroll
            for (int r = 0; r < 4; r++) {
                int o = o0 + mc * 16 + lhi * 4 + r;
                int i = i0 + nc * 16 + l15;
                vT[(size_t)(b * C_ + o) * N_ + i] = (f16)(acc[mc][nc][r] + bia[r]);
            }
    }
}

// ---------------- 4. flash attention, KV-split, LDS-staged K and V ----------
__device__ __forceinline__ void stage_tile(const f16* kbase, f16* dst, int j0,
                                           int w, int l) {
    #pragma unroll
    for (int rd = 0; rd < 4; rd++) {
        int cb = (rd * 4 + w) * 64;          // wave-uniform chunk base
        int mc = cb + l;                     // this lane's 16B chunk
        int row = mc >> 5;                   // 32 chunks (512B) per row
        int xoff = ((mc & 31) << 4) ^ ((row & 7) << 4);
        const f16* gsrc = kbase + (size_t)(j0 + row) * C_ + (xoff >> 1);
        __builtin_amdgcn_global_load_lds(
            (const __attribute__((address_space(1))) void*)gsrc,
            (__attribute__((address_space(3))) void*)(dst + (size_t)cb * 8),
            16, 0, 0);
    }
}

__global__ __launch_bounds__(256, 2) void flash_split_kernel(
    const f16* __restrict__ q, const f16* __restrict__ k,
    const f16* __restrict__ vT,
    f16* __restrict__ o0p, f16* __restrict__ o1p,
    float2* __restrict__ stats)
{
    // XCD-pinned decode: linear block id % 8 selects XCD (HW round-robin);
    // group g = (b,split) so each XCD's K/V working set (2 MB) is L2-resident.
    int bi = blockIdx.x;
    int g = bi & 7;
    int it = bi >> 3;                 // 0..63
    int b = g >> 1, split = g & 1;
    int tid = threadIdx.x, w = tid >> 6, l = tid & 63;
    int l15 = l & 15, lhi = l >> 4;
    int i0 = it * 64 + w * 16;
    int jt0 = split * JT_PER;
    __shared__ __align__(16) f16 kb[2][32][256];   // 32 KB, XOR-swizzled
    __shared__ __align__(16) f16 vlds[256][40];    // 20 KB, padded rows (80B)
    __shared__ __align__(16) f16 P[4][16][40];     // 5 KB

    const f16* kbase = k + (size_t)b * N_ * C_;
    const f16* vbase = vT + (size_t)b * C_ * N_;

    f16v8 qf[8];
    size_t qrow = (size_t)(b * N_ + i0 + l15) * C_ + lhi * 8;
    #pragma unroll
    for (int kk = 0; kk < 8; kk++) qf[kk] = ldh(q + qrow + kk * 32);

    f32x4 oacc[16];
    #pragma unroll
    for (int cc = 0; cc < 16; cc++) oacc[cc] = (f32x4){0.f, 0.f, 0.f, 0.f};
    float m[4], lsum[4];
    #pragma unroll
    for (int r = 0; r < 4; r++) { m[r] = -1e30f; lsum[r] = 0.f; }

    int vrow = tid >> 2;              // 0..63 (plus u*64)
    int vcol = (tid & 3) * 8;

    stage_tile(kbase, &kb[0][0][0], jt0 * 32, w, l);
    __syncthreads();

    for (int jt = 0; jt < JT_PER; jt++) {
        int cur = jt & 1;
        int j0 = (jt0 + jt) * 32;

        // V tile -> regs FIRST (so ds_write's vmcnt wait leaves K in flight)
        f16v8 vreg[4];
        #pragma unroll
        for (int u = 0; u < 4; u++)
            vreg[u] = ldh(vbase + (size_t)(u * 64 + vrow) * N_ + j0 + vcol);

        if (jt + 1 < JT_PER)
            stage_tile(kbase, &kb[cur ^ 1][0][0], j0 + 32, w, l);

        // ---- QK^T from LDS (swizzled read) ----
        const char* kbc = (const char*)&kb[cur][0][0];
        f32x4 s[2];
        s[0] = (f32x4){0.f, 0.f, 0.f, 0.f};
        s[1] = (f32x4){0.f, 0.f, 0.f, 0.f};
        #pragma unroll
        for (int kk = 0; kk < 8; kk++) {
            #pragma unroll
            for (int jc = 0; jc < 2; jc++) {
                int row = jc * 16 + l15;
                int off = row * 512 + ((kk * 64 + lhi * 16) ^ ((row & 7) << 4));
                f16v8 kf = *reinterpret_cast<const f16v8*>(kbc + off);
                s[jc] = mfma16(qf[kk], kf, s[jc]);
            }
        }

        // ---- online softmax (rows = i0 + lhi*4 + r) ----
        float sc[4];
        #pragma unroll
        for (int r = 0; r < 4; r++) {
            float mt = fmaxf(s[0][r], s[1][r]);
            #pragma unroll
            for (int mask = 1; mask < 16; mask <<= 1)
                mt = fmaxf(mt, __shfl_xor(mt, mask));
            float mn = fmaxf(m[r], mt);
            sc[r] = __expf(m[r] - mn);
            m[r] = mn;
        }
        float p0[4], p1[4], rsum[4];
        #pragma unroll
        for (int r = 0; r < 4; r++) {
            p0[r] = __expf(s[0][r] - m[r]);
            p1[r] = __expf(s[1][r] - m[r]);
            rsum[r] = p0[r] + p1[r];
            #pragma unroll
            for (int mask = 1; mask < 16; mask <<= 1)
                rsum[r] += __shfl_xor(rsum[r], mask);
            lsum[r] = lsum[r] * sc[r] + rsum[r];
        }
        #pragma unroll
        for (int cc = 0; cc < 16; cc++) {
            #pragma unroll
            for (int r = 0; r < 4; r++) oacc[cc][r] *= sc[r];
        }

        // ---- V regs -> LDS (prev-iter PV readers already past barrier B) ----
        #pragma unroll
        for (int u = 0; u < 4; u++)
            *reinterpret_cast<f16v8*>(&vlds[u * 64 + vrow][vcol]) = vreg[u];

        // ---- P (D-frag) -> LDS (wave-local) ----
        #pragma unroll
        for (int r = 0; r < 4; r++) {
            P[w][lhi * 4 + r][l15]      = (f16)p0[r];
            P[w][lhi * 4 + r][16 + l15] = (f16)p1[r];
        }

        __syncthreads();   // A: V visible to all waves; K(jt+1) drained

        f16v8 pf = *reinterpret_cast<const f16v8*>(&P[w][l15][lhi * 8]);

        // ---- O += P @ V (V from padded LDS, conflict-free) ----
        #pragma unroll
        for (int cc = 0; cc < 16; cc++) {
            f16v8 vf = *reinterpret_cast<const f16v8*>(&vlds[cc * 16 + l15][lhi * 8]);
            oacc[cc] = mfma16(pf, vf, oacc[cc]);
        }

        // B: WAR guard for vlds (no vmcnt drain; ds_reads already lgkm-waited)
        __builtin_amdgcn_sched_barrier(0);
        __builtin_amdgcn_s_barrier();
        __builtin_amdgcn_sched_barrier(0);
    }

    f16* op = split ? o1p : o0p;
    float inv[4];
    #pragma unroll
    for (int r = 0; r < 4; r++) inv[r] = 1.f / lsum[r];
    #pragma unroll
    for (int cc = 0; cc < 16; cc++)
        #pragma unroll
        for (int r = 0; r < 4; r++)
            op[(size_t)(b * N_ + i0 + lhi * 4 + r) * C_ + cc * 16 + l15] =
                (f16)(oacc[cc][r] * inv[r]);
    if (l15 == 0) {
        #pragma unroll
        for (int r = 0; r < 4; r++)
            stats[((size_t)split * B_ + b) * N_ + i0 + lhi * 4 + r] =
                make_float2(m[r], lsum[r]);
    }
}

// ---------------- 4b. combine partials ----------------
__global__ __launch_bounds__(256) void combine_kernel(
    const f16* __restrict__ o0p, const f16* __restrict__ o1p,
    const float2* __restrict__ stats, f16* __restrict__ att)
{
    int it = blockIdx.x, b = blockIdx.y;
    int tid = threadIdx.x;
    int row = it * 64 + (tid >> 2);
    int c0 = (tid & 3) * 64;
    const f16* ops[SPLITS] = {o0p, o1p};
    float2 st[SPLITS];
    float M = -1e30f;
    #pragma unroll
    for (int s = 0; s < SPLITS; s++) {
        st[s] = stats[((size_t)s * B_ + b) * N_ + row];
        M = fmaxf(M, st[s].x);
    }
    float wgt[SPLITS], L = 0.f;
    #pragma unroll
    for (int s = 0; s < SPLITS; s++) {
        wgt[s] = st[s].y * __expf(st[s].x - M);
        L += wgt[s];
    }
    float inv = 1.f / L;
    #pragma unroll
    for (int s = 0; s < SPLITS; s++) wgt[s] *= inv;
    size_t base = (size_t)(b * N_ + row) * C_ + c0;
    #pragma unroll
    for (int u = 0; u < 8; u++) {
        float a[8];
        #pragma unroll
        for (int e = 0; e < 8; e++) a[e] = 0.f;
        #pragma unroll
        for (int s = 0; s < SPLITS; s++) {
            f16v8 v = ldh(ops[s] + base + u * 8);
            #pragma unroll
            for (int e = 0; e < 8; e++) a[e] += wgt[s] * (float)v[e];
        }
        f16v8 o;
        #pragma unroll
        for (int e = 0; e < 8; e++) o[e] = (f16)a[e];
        *reinterpret_cast<f16v8*>(att + base + u * 8) = o;
    }
}

// ---------------- 5. conv_o + bias + residual ----------------
__global__ __launch_bounds__(256) void final_kernel(
    const f16* __restrict__ att, const f16* __restrict__ wo16,
    const float* __restrict__ bo, const float* __restrict__ x,
    float* __restrict__ out)
{
    int it = blockIdx.x, b = blockIdx.y;
    int tid = threadIdx.x, w = tid >> 6, l = tid & 63;
    int l15 = l & 15, lhi = l >> 4;
    int o0 = w * 64, i0 = it * 64;
    f32x4 acc[4][4];
    #pragma unroll
    for (int mc = 0; mc < 4; mc++)
        #pragma unroll
        for (int nc = 0; nc < 4; nc++) acc[mc][nc] = (f32x4){0.f, 0.f, 0.f, 0.f};
    for (int kk = 0; kk < 8; kk++) {
        f16v8 af[4], bfv[4];
        #pragma unroll
        for (int mc = 0; mc < 4; mc++)
            af[mc] = ldh(wo16 + (size_t)(o0 + mc * 16 + l15) * C_ + kk * 32 + lhi * 8);
        #pragma unroll
        for (int nc = 0; nc < 4; nc++)
            bfv[nc] = ldh(att + (size_t)(b * N_ + i0 + nc * 16 + l15) * C_ + kk * 32 + lhi * 8);
        #pragma unroll
        for (int mc = 0; mc < 4; mc++)
            #pragma unroll
            for (int nc = 0; nc < 4; nc++)
                acc[mc][nc] = mfma16(af[mc], bfv[nc], acc[mc][nc]);
    }
    #pragma unroll
    for (int mc = 0; mc < 4; mc++) {
        float bia[4];
        #pragma unroll
        for (int r = 0; r < 4; r++) bia[r] = bo[o0 + mc * 16 + lhi * 4 + r];
        #pragma unroll
        for (int nc = 0; nc < 4; nc++)
            #pragma unroll
            for (int r = 0; r < 4; r++) {
                int o = o0 + mc * 16 + lhi * 4 + r;
                int i = i0 + nc * 16 + l15;
                size_t idx = (size_t)(b * C_ + o) * N_ + i;
                out[idx] = x[idx] + acc[mc][nc][r] + bia[r];
            }
    }
}

extern "C" void kernel_launch(void* const* d_in, const int* in_sizes, int n_in,
                              void* d_out, int out_size, void* d_ws, size_t ws_size,
                              hipStream_t stream) {
    const float* x  = (const float*)d_in[0];
    const float* gg = (const float*)d_in[1];
    const float* gb = (const float*)d_in[2];
    const float* wq = (const float*)d_in[3];
    const float* bq = (const float*)d_in[4];
    const float* wk = (const float*)d_in[5];
    const float* bk = (const float*)d_in[6];
    const float* wv = (const float*)d_in[7];
    const float* bv = (const float*)d_in[8];
    const float* wo = (const float*)d_in[9];
    const float* bo = (const float*)d_in[10];
    float* out = (float*)d_out;

    char* p = (char*)d_ws;
    const size_t WSZ = (size_t)C_ * C_ * 2;       // 128 KB per fp16 weight
    const size_t HSZ = (size_t)B_ * N_ * C_ * 2;  // 8 MB per fp16 activation
    f16* wq16 = (f16*)p; p += WSZ;
    f16* wk16 = (f16*)p; p += WSZ;
    f16* wv16 = (f16*)p; p += WSZ;
    f16* wo16 = (f16*)p; p += WSZ;
    f16* hn   = (f16*)p; p += HSZ;
    f16* qo   = (f16*)p; p += HSZ;
    f16* ko   = (f16*)p; p += HSZ;
    f16* vt   = (f16*)p; p += HSZ;
    f16* o1p  = (f16*)p; p += HSZ;                // split-1 partial
    float2* stats = (float2*)p; p += (size_t)SPLITS * B_ * N_ * sizeof(float2);

    f16* o0p = hn;            // hn dead after projections; split-0 partial
    f16* att = qo;            // qo dead after flash; combined output

    conv_w_kernel<<<dim3(C_ * C_ / 256), 256, 0, stream>>>(
        wq, wk, wv, wo, wq16, wk16, wv16, wo16);
    gn_kernel<<<dim3(B_ * NG_), 256, 0, stream>>>(x, gg, gb, hn);
    proj_qk_kernel<<<dim3(N_ / 64, B_, 2), 256, 0, stream>>>(
        hn, wq16, wk16, bq, bk, qo, ko);
    proj_v_kernel<<<dim3(N_ / 64, B_), 256, 0, stream>>>(hn, wv16, bv, vt);
    flash_split_kernel<<<dim3(N_ / 64 * B_ * SPLITS), 256, 0, stream>>>(
        qo, ko, vt, o0p, o1p, stats);
    combine_kernel<<<dim3(N_ / 64, B_), 256, 0, stream>>>(
        o0p, o1p, stats, att);
    final_kernel<<<dim3(N_ / 64, B_), 256, 0, stream>>>(att, wo16, bo, x, out);
}

// Round 6
// 232.715 us; speedup vs baseline: 3.7700x; 1.2355x over previous
//
#include <hip/hip_runtime.h>
#include <hip/hip_bf16.h>

#define C_ 256
#define N_ 4096
#define B_ 4
#define NG_ 32
#define CPG_ 8
#define SPLITS 2
#define JT_PER (N_ / 32 / SPLITS)   // 64 j-tiles of 32 per split

typedef _Float16 f16;
typedef __attribute__((ext_vector_type(8))) _Float16 f16v8;
typedef __attribute__((ext_vector_type(2))) __fp16 fp16v2;
typedef __attribute__((ext_vector_type(4))) float f32x4;

__device__ __forceinline__ f16v8 ldh(const f16* p) {
    return *reinterpret_cast<const f16v8*>(p);
}
__device__ __forceinline__ f32x4 mfma16(f16v8 a, f16v8 b, f32x4 c) {
    return __builtin_amdgcn_mfma_f32_16x16x32_f16(a, b, c, 0, 0, 0);
}
__device__ __forceinline__ unsigned int pkh(float a, float b) {
    fp16v2 t = __builtin_amdgcn_cvt_pkrtz(a, b);
    return __builtin_bit_cast(unsigned int, t);
}

// ---------------- 0. weights fp32 -> fp16 ----------------
__global__ __launch_bounds__(256) void conv_w_kernel(
    const float* __restrict__ wq, const float* __restrict__ wk,
    const float* __restrict__ wv, const float* __restrict__ wo,
    f16* __restrict__ wq16, f16* __restrict__ wk16,
    f16* __restrict__ wv16, f16* __restrict__ wo16)
{
    int idx = blockIdx.x * 256 + threadIdx.x;   // 65536 elements
    wq16[idx] = (f16)wq[idx];
    wk16[idx] = (f16)wk[idx];
    wv16[idx] = (f16)wv[idx];
    wo16[idx] = (f16)wo[idx];
}

// ---------------- 1. GroupNorm -> hn^T [b][n][c] fp16 ----------------
__global__ __launch_bounds__(256) void gn_kernel(
    const float* __restrict__ x, const float* __restrict__ gamma,
    const float* __restrict__ beta, f16* __restrict__ hn)
{
    int b = blockIdx.x >> 5, g = blockIdx.x & 31;
    const float* xp = x + (size_t)(b * C_ + g * CPG_) * N_;
    int tid = threadIdx.x;
    float s = 0.f, s2 = 0.f;
    for (int idx = tid; idx < CPG_ * N_; idx += 256) {
        float v = xp[idx];
        s += v; s2 += v * v;
    }
    #pragma unroll
    for (int off = 32; off > 0; off >>= 1) {
        s  += __shfl_down(s, off);
        s2 += __shfl_down(s2, off);
    }
    __shared__ float rs[4], rs2[4], stat[2];
    if ((tid & 63) == 0) { rs[tid >> 6] = s; rs2[tid >> 6] = s2; }
    __syncthreads();
    if (tid == 0) {
        float S  = rs[0] + rs[1] + rs[2] + rs[3];
        float S2 = rs2[0] + rs2[1] + rs2[2] + rs2[3];
        float mean = S / (float)(CPG_ * N_);
        float var  = S2 / (float)(CPG_ * N_) - mean * mean;
        stat[0] = mean;
        stat[1] = rsqrtf(var + 1e-6f);
    }
    __syncthreads();
    float mean = stat[0], rstd = stat[1];
    float ga[CPG_], be[CPG_];
    #pragma unroll
    for (int cc = 0; cc < CPG_; cc++) {
        ga[cc] = gamma[g * CPG_ + cc] * rstd;
        be[cc] = beta[g * CPG_ + cc];
    }
    for (int i = tid; i < N_; i += 256) {
        f16v8 H;
        #pragma unroll
        for (int cc = 0; cc < CPG_; cc++)
            H[cc] = (f16)((xp[(size_t)cc * N_ + i] - mean) * ga[cc] + be[cc]);
        *reinterpret_cast<f16v8*>(hn + (size_t)(b * N_ + i) * C_ + g * CPG_) = H;
    }
}

// ---------------- 2. q/k projection ----------------
__global__ __launch_bounds__(256) void proj_qk_kernel(
    const f16* __restrict__ hn, const f16* __restrict__ wq16,
    const f16* __restrict__ wk16, const float* __restrict__ bq,
    const float* __restrict__ bk, f16* __restrict__ qo, f16* __restrict__ ko)
{
    int it = blockIdx.x, b = blockIdx.y, which = blockIdx.z;
    const f16* wgt = which ? wk16 : wq16;
    const float* bias = which ? bk : bq;
    f16* outp = which ? ko : qo;
    int tid = threadIdx.x, w = tid >> 6, l = tid & 63;
    int l15 = l & 15, lhi = l >> 4;
    int i0 = it * 64 + w * 16;
    size_t arow = (size_t)(b * N_ + i0 + l15) * C_ + lhi * 8;
    f16v8 af[8];
    #pragma unroll
    for (int kk = 0; kk < 8; kk++) af[kk] = ldh(hn + arow + kk * 32);
    for (int oc = 0; oc < 16; oc++) {
        f32x4 acc = {0.f, 0.f, 0.f, 0.f};
        size_t wrow = (size_t)(oc * 16 + l15) * C_ + lhi * 8;
        #pragma unroll
        for (int kk = 0; kk < 8; kk++)
            acc = mfma16(af[kk], ldh(wgt + wrow + kk * 32), acc);
        float bia = bias[oc * 16 + l15];
        #pragma unroll
        for (int r = 0; r < 4; r++)
            outp[(size_t)(b * N_ + i0 + lhi * 4 + r) * C_ + oc * 16 + l15] =
                (f16)(acc[r] + bia);
    }
}

// ---------------- 3. v projection -> v^T [b][c][n] fp16 ----------------
__global__ __launch_bounds__(256) void proj_v_kernel(
    const f16* __restrict__ hn, const f16* __restrict__ wv16,
    const float* __restrict__ bv, f16* __restrict__ vT)
{
    int it = blockIdx.x, b = blockIdx.y;
    int tid = threadIdx.x, w = tid >> 6, l = tid & 63;
    int l15 = l & 15, lhi = l >> 4;
    int o0 = w * 64, i0 = it * 64;
    f32x4 acc[4][4];
    #pragma unroll
    for (int mc = 0; mc < 4; mc++)
        #pragma unroll
        for (int nc = 0; nc < 4; nc++) acc[mc][nc] = (f32x4){0.f, 0.f, 0.f, 0.f};
    for (int kk = 0; kk < 8; kk++) {
        f16v8 af[4], bfv[4];
        #pragma unroll
        for (int mc = 0; mc < 4; mc++)
            af[mc] = ldh(wv16 + (size_t)(o0 + mc * 16 + l15) * C_ + kk * 32 + lhi * 8);
        #pragma unroll
        for (int nc = 0; nc < 4; nc++)
            bfv[nc] = ldh(hn + (size_t)(b * N_ + i0 + nc * 16 + l15) * C_ + kk * 32 + lhi * 8);
        #pragma unroll
        for (int mc = 0; mc < 4; mc++)
            #pragma unroll
            for (int nc = 0; nc < 4; nc++)
                acc[mc][nc] = mfma16(af[mc], bfv[nc], acc[mc][nc]);
    }
    #pragma unroll
    for (int mc = 0; mc < 4; mc++) {
        float bia[4];
        #pragma unroll
        for (int r = 0; r < 4; r++) bia[r] = bv[o0 + mc * 16 + lhi * 4 + r];
        #pragma unroll
        for (int nc = 0; nc < 4; nc++)
            #pragma unroll
            for (int r = 0; r < 4; r++) {
                int o = o0 + mc * 16 + lhi * 4 + r;
                int i = i0 + nc * 16 + l15;
                vT[(size_t)(b * C_ + o) * N_ + i] = (f16)(acc[mc][nc][r] + bia[r]);
            }
    }
}

// ---------------- 4. flash attention, swapped-QK^T, KV-split ----------------
__device__ __forceinline__ void stage_tile(const f16* kbase, f16* dst, int j0,
                                           int w, int l) {
    #pragma unroll
    for (int rd = 0; rd < 4; rd++) {
        int cb = (rd * 4 + w) * 64;          // wave-uniform chunk base
        int mc = cb + l;                     // this lane's 16B chunk
        int row = mc >> 5;                   // 32 chunks (512B) per row
        int xoff = ((mc & 31) << 4) ^ ((row & 7) << 4);
        const f16* gsrc = kbase + (size_t)(j0 + row) * C_ + (xoff >> 1);
        __builtin_amdgcn_global_load_lds(
            (const __attribute__((address_space(1))) void*)gsrc,
            (__attribute__((address_space(3))) void*)(dst + (size_t)cb * 8),
            16, 0, 0);
    }
}

__global__ __launch_bounds__(256, 2) void flash_split_kernel(
    const f16* __restrict__ q, const f16* __restrict__ k,
    const f16* __restrict__ vT,
    f16* __restrict__ o0p, f16* __restrict__ o1p,
    float2* __restrict__ stats)
{
    // XCD-pinned: linear id % 8 -> XCD; group = (b,split), 2MB K/V L2-resident.
    int bi = blockIdx.x;
    int g = bi & 7;
    int it = bi >> 3;                 // 0..63
    int b = g >> 1, split = g & 1;
    int tid = threadIdx.x, w = tid >> 6, l = tid & 63;
    int l15 = l & 15, lhi = l >> 4;
    int i0 = it * 64 + w * 16;
    int jt0 = split * JT_PER;
    __shared__ __align__(16) f16 kb[2][32][256];     // 32 KB, XOR-swizzled
    __shared__ __align__(16) f16 vlds[256][40];      // 20 KB, padded rows
    __shared__ __align__(16) unsigned int Plds[4][16][20];  // 5 KB, [i][jpair]

    const f16* kbase = k + (size_t)b * N_ * C_;
    const f16* vbase = vT + (size_t)b * C_ * N_;

    f16v8 qf[8];
    size_t qrow = (size_t)(b * N_ + i0 + l15) * C_ + lhi * 8;
    #pragma unroll
    for (int kk = 0; kk < 8; kk++) qf[kk] = ldh(q + qrow + kk * 32);

    // oacc[cc][r] = O^T[c = cc*16 + lhi*4 + r][i = i0 + l15]
    f32x4 oacc[16];
    #pragma unroll
    for (int cc = 0; cc < 16; cc++) oacc[cc] = (f32x4){0.f, 0.f, 0.f, 0.f};
    float m = -1e30f, rsum = 0.f;    // per-lane: row i = i0 + l15

    int vrow = tid >> 2;             // 0..63 (plus u*64)
    int vcol = (tid & 3) * 8;

    stage_tile(kbase, &kb[0][0][0], jt0 * 32, w, l);
    __syncthreads();

    for (int jt = 0; jt < JT_PER; jt++) {
        int cur = jt & 1;
        int j0 = (jt0 + jt) * 32;

        // V tile -> regs FIRST (vmcnt clears before K prefetch)
        f16v8 vreg[4];
        #pragma unroll
        for (int u = 0; u < 4; u++)
            vreg[u] = ldh(vbase + (size_t)(u * 64 + vrow) * N_ + j0 + vcol);

        if (jt + 1 < JT_PER)
            stage_tile(kbase, &kb[cur ^ 1][0][0], j0 + 32, w, l);

        // ---- swapped QK^T: s'[j][i] = mfma(K, Q) ----
        const char* kbc = (const char*)&kb[cur][0][0];
        f32x4 s0 = {0.f, 0.f, 0.f, 0.f};
        f32x4 s1 = {0.f, 0.f, 0.f, 0.f};
        #pragma unroll
        for (int kk = 0; kk < 8; kk++) {
            {
                int row = l15;
                int off = row * 512 + ((kk * 64 + lhi * 16) ^ ((row & 7) << 4));
                f16v8 kf = *reinterpret_cast<const f16v8*>(kbc + off);
                s0 = mfma16(kf, qf[kk], s0);
            }
            {
                int row = 16 + l15;
                int off = row * 512 + ((kk * 64 + lhi * 16) ^ ((row & 7) << 4));
                f16v8 kf = *reinterpret_cast<const f16v8*>(kbc + off);
                s1 = mfma16(kf, qf[kk], s1);
            }
        }
        // lane (l15, lhi) holds s'[j = {lhi*4+r, 16+lhi*4+r}][i = i0+l15]

        // ---- per-lane online softmax (row i = i0 + l15) ----
        float mt = fmaxf(fmaxf(fmaxf(s0[0], s0[1]), fmaxf(s0[2], s0[3])),
                         fmaxf(fmaxf(s1[0], s1[1]), fmaxf(s1[2], s1[3])));
        mt = fmaxf(mt, __shfl_xor(mt, 16));
        mt = fmaxf(mt, __shfl_xor(mt, 32));
        float mn = fmaxf(m, mt);
        float sc = __expf(m - mn);
        m = mn;
        float p0[4], p1[4];
        float ls = 0.f;
        #pragma unroll
        for (int r = 0; r < 4; r++) {
            p0[r] = __expf(s0[r] - m);
            p1[r] = __expf(s1[r] - m);
            ls += p0[r] + p1[r];
        }
        rsum = rsum * sc + ls;       // deferred cross-lane reduce
        #pragma unroll
        for (int cc = 0; cc < 16; cc++) {
            #pragma unroll
            for (int r = 0; r < 4; r++) oacc[cc][r] *= sc;
        }

        // ---- V regs -> LDS ----
        #pragma unroll
        for (int u = 0; u < 4; u++)
            *reinterpret_cast<f16v8*>(&vlds[u * 64 + vrow][vcol]) = vreg[u];

        // ---- P' -> LDS transposed ([i][j-pair]) for B-frag read ----
        uint2 pa = {pkh(p0[0], p0[1]), pkh(p0[2], p0[3])};
        uint2 pb = {pkh(p1[0], p1[1]), pkh(p1[2], p1[3])};
        *reinterpret_cast<uint2*>(&Plds[w][l15][lhi * 2])     = pa;
        *reinterpret_cast<uint2*>(&Plds[w][l15][8 + lhi * 2]) = pb;

        __syncthreads();   // V visible to all waves; K(jt+1) drained

        // B-frag: lane (l15=i, lhi) reads P'[j=lhi*8..+7][i=l15]
        f16v8 pfB = *reinterpret_cast<const f16v8*>(&Plds[w][l15][lhi * 4]);

        // ---- O^T += V^T @ P' ----
        #pragma unroll
        for (int cc = 0; cc < 16; cc++) {
            f16v8 vf = *reinterpret_cast<const f16v8*>(&vlds[cc * 16 + l15][lhi * 8]);
            oacc[cc] = mfma16(vf, pfB, oacc[cc]);
        }

        // WAR guard for vlds (no vmcnt drain)
        __builtin_amdgcn_sched_barrier(0);
        __builtin_amdgcn_s_barrier();
        __builtin_amdgcn_sched_barrier(0);
    }

    // final cross-lane lsum reduce (4 lanes share row i)
    rsum += __shfl_xor(rsum, 16);
    rsum += __shfl_xor(rsum, 32);
    float inv = 1.f / rsum;

    f16* op = split ? o1p : o0p;
    size_t obase = (size_t)(b * N_ + i0 + l15) * C_;
    #pragma unroll
    for (int cc = 0; cc < 16; cc++) {
        uint2 st = {pkh(oacc[cc][0] * inv, oacc[cc][1] * inv),
                    pkh(oacc[cc][2] * inv, oacc[cc][3] * inv)};
        *reinterpret_cast<uint2*>(op + obase + cc * 16 + lhi * 4) = st;
    }
    if (lhi == 0)
        stats[((size_t)split * B_ + b) * N_ + i0 + l15] = make_float2(m, rsum);
}

// ---------------- 5. fused combine + conv_o + bias + residual ----------------
__global__ __launch_bounds__(256) void final_kernel(
    const f16* __restrict__ o0p, const f16* __restrict__ o1p,
    const float2* __restrict__ stats, const f16* __restrict__ wo16,
    const float* __restrict__ bo, const float* __restrict__ x,
    float* __restrict__ out)
{
    int it = blockIdx.x, b = blockIdx.y;
    int tid = threadIdx.x, w = tid >> 6, l = tid & 63;
    int l15 = l & 15, lhi = l >> 4;
    int o0 = w * 64, i0 = it * 64;

    // per-row split weights (row = i0 + nc*16 + l15)
    f16 w0h[4], w1h[4];
    #pragma unroll
    for (int nc = 0; nc < 4; nc++) {
        int row = i0 + nc * 16 + l15;
        float2 s0 = stats[(size_t)b * N_ + row];
        float2 s1 = stats[((size_t)B_ + b) * N_ + row];
        float M = fmaxf(s0.x, s1.x);
        float a0 = s0.y * __expf(s0.x - M);
        float a1 = s1.y * __expf(s1.x - M);
        float inv = 1.f / (a0 + a1);
        w0h[nc] = (f16)(a0 * inv);
        w1h[nc] = (f16)(a1 * inv);
    }

    f32x4 acc[4][4];
    #pragma unroll
    for (int mc = 0; mc < 4; mc++)
        #pragma unroll
        for (int nc = 0; nc < 4; nc++) acc[mc][nc] = (f32x4){0.f, 0.f, 0.f, 0.f};
    for (int kk = 0; kk < 8; kk++) {
        f16v8 af[4], bfv[4];
        #pragma unroll
        for (int mc = 0; mc < 4; mc++)
            af[mc] = ldh(wo16 + (size_t)(o0 + mc * 16 + l15) * C_ + kk * 32 + lhi * 8);
        #pragma unroll
        for (int nc = 0; nc < 4; nc++) {
            size_t off = (size_t)(b * N_ + i0 + nc * 16 + l15) * C_ + kk * 32 + lhi * 8;
            f16v8 a = ldh(o0p + off);
            f16v8 c = ldh(o1p + off);
            bfv[nc] = a * w0h[nc] + c * w1h[nc];
        }
        #pragma unroll
        for (int mc = 0; mc < 4; mc++)
            #pragma unroll
            for (int nc = 0; nc < 4; nc++)
                acc[mc][nc] = mfma16(af[mc], bfv[nc], acc[mc][nc]);
    }
    #pragma unroll
    for (int mc = 0; mc < 4; mc++) {
        float bia[4];
        #pragma unroll
        for (int r = 0; r < 4; r++) bia[r] = bo[o0 + mc * 16 + lhi * 4 + r];
        #pragma unroll
        for (int nc = 0; nc < 4; nc++)
            #pragma unroll
            for (int r = 0; r < 4; r++) {
                int o = o0 + mc * 16 + lhi * 4 + r;
                int i = i0 + nc * 16 + l15;
                size_t idx = (size_t)(b * C_ + o) * N_ + i;
                out[idx] = x[idx] + acc[mc][nc][r] + bia[r];
            }
    }
}

extern "C" void kernel_launch(void* const* d_in, const int* in_sizes, int n_in,
                              void* d_out, int out_size, void* d_ws, size_t ws_size,
                              hipStream_t stream) {
    const float* x  = (const float*)d_in[0];
    const float* gg = (const float*)d_in[1];
    const float* gb = (const float*)d_in[2];
    const float* wq = (const float*)d_in[3];
    const float* bq = (const float*)d_in[4];
    const float* wk = (const float*)d_in[5];
    const float* bk = (const float*)d_in[6];
    const float* wv = (const float*)d_in[7];
    const float* bv = (const float*)d_in[8];
    const float* wo = (const float*)d_in[9];
    const float* bo = (const float*)d_in[10];
    float* out = (float*)d_out;

    char* p = (char*)d_ws;
    const size_t WSZ = (size_t)C_ * C_ * 2;       // 128 KB per fp16 weight
    const size_t HSZ = (size_t)B_ * N_ * C_ * 2;  // 8 MB per fp16 activation
    f16* wq16 = (f16*)p; p += WSZ;
    f16* wk16 = (f16*)p; p += WSZ;
    f16* wv16 = (f16*)p; p += WSZ;
    f16* wo16 = (f16*)p; p += WSZ;
    f16* hn   = (f16*)p; p += HSZ;
    f16* qo   = (f16*)p; p += HSZ;
    f16* ko   = (f16*)p; p += HSZ;
    f16* vt   = (f16*)p; p += HSZ;
    f16* o1p  = (f16*)p; p += HSZ;                // split-1 partial
    float2* stats = (float2*)p; p += (size_t)SPLITS * B_ * N_ * sizeof(float2);

    f16* o0p = hn;            // hn dead after projections; split-0 partial

    conv_w_kernel<<<dim3(C_ * C_ / 256), 256, 0, stream>>>(
        wq, wk, wv, wo, wq16, wk16, wv16, wo16);
    gn_kernel<<<dim3(B_ * NG_), 256, 0, stream>>>(x, gg, gb, hn);
    proj_qk_kernel<<<dim3(N_ / 64, B_, 2), 256, 0, stream>>>(
        hn, wq16, wk16, bq, bk, qo, ko);
    proj_v_kernel<<<dim3(N_ / 64, B_), 256, 0, stream>>>(hn, wv16, bv, vt);
    flash_split_kernel<<<dim3(N_ / 64 * B_ * SPLITS), 256, 0, stream>>>(
        qo, ko, vt, o0p, o1p, stats);
    final_kernel<<<dim3(N_ / 64, B_), 256, 0, stream>>>(
        o0p, o1p, stats, wo16, bo, x, out);
}

// Round 7
// 231.878 us; speedup vs baseline: 3.7836x; 1.0036x over previous
//
#include <hip/hip_runtime.h>
#include <hip/hip_bf16.h>

#define C_ 256
#define N_ 4096
#define B_ 4
#define NG_ 32
#define CPG_ 8
#define SPLITS 2
#define JT_PER (N_ / 32 / SPLITS)   // 64 j-tiles of 32 per split

typedef _Float16 f16;
typedef __attribute__((ext_vector_type(8))) _Float16 f16v8;
typedef __attribute__((ext_vector_type(2))) __fp16 fp16v2;
typedef __attribute__((ext_vector_type(4))) float f32x4;

__device__ __forceinline__ f16v8 ldh(const f16* p) {
    return *reinterpret_cast<const f16v8*>(p);
}
__device__ __forceinline__ f32x4 mfma16(f16v8 a, f16v8 b, f32x4 c) {
    return __builtin_amdgcn_mfma_f32_16x16x32_f16(a, b, c, 0, 0, 0);
}
__device__ __forceinline__ unsigned int pkh(float a, float b) {
    fp16v2 t = __builtin_amdgcn_cvt_pkrtz(a, b);
    return __builtin_bit_cast(unsigned int, t);
}

// ---------------- 0. weights fp32 -> fp16 ----------------
__global__ __launch_bounds__(256) void conv_w_kernel(
    const float* __restrict__ wq, const float* __restrict__ wk,
    const float* __restrict__ wv, const float* __restrict__ wo,
    f16* __restrict__ wq16, f16* __restrict__ wk16,
    f16* __restrict__ wv16, f16* __restrict__ wo16)
{
    int idx = blockIdx.x * 256 + threadIdx.x;   // 65536 elements
    wq16[idx] = (f16)wq[idx];
    wk16[idx] = (f16)wk[idx];
    wv16[idx] = (f16)wv[idx];
    wo16[idx] = (f16)wo[idx];
}

// ---------------- 1. GroupNorm -> hn^T [b][n][c] fp16 ----------------
__global__ __launch_bounds__(256) void gn_kernel(
    const float* __restrict__ x, const float* __restrict__ gamma,
    const float* __restrict__ beta, f16* __restrict__ hn)
{
    int b = blockIdx.x >> 5, g = blockIdx.x & 31;
    const float* xp = x + (size_t)(b * C_ + g * CPG_) * N_;
    int tid = threadIdx.x;
    float s = 0.f, s2 = 0.f;
    for (int idx = tid; idx < CPG_ * N_; idx += 256) {
        float v = xp[idx];
        s += v; s2 += v * v;
    }
    #pragma unroll
    for (int off = 32; off > 0; off >>= 1) {
        s  += __shfl_down(s, off);
        s2 += __shfl_down(s2, off);
    }
    __shared__ float rs[4], rs2[4], stat[2];
    if ((tid & 63) == 0) { rs[tid >> 6] = s; rs2[tid >> 6] = s2; }
    __syncthreads();
    if (tid == 0) {
        float S  = rs[0] + rs[1] + rs[2] + rs[3];
        float S2 = rs2[0] + rs2[1] + rs2[2] + rs2[3];
        float mean = S / (float)(CPG_ * N_);
        float var  = S2 / (float)(CPG_ * N_) - mean * mean;
        stat[0] = mean;
        stat[1] = rsqrtf(var + 1e-6f);
    }
    __syncthreads();
    float mean = stat[0], rstd = stat[1];
    float ga[CPG_], be[CPG_];
    #pragma unroll
    for (int cc = 0; cc < CPG_; cc++) {
        ga[cc] = gamma[g * CPG_ + cc] * rstd;
        be[cc] = beta[g * CPG_ + cc];
    }
    for (int i = tid; i < N_; i += 256) {
        f16v8 H;
        #pragma unroll
        for (int cc = 0; cc < CPG_; cc++)
            H[cc] = (f16)((xp[(size_t)cc * N_ + i] - mean) * ga[cc] + be[cc]);
        *reinterpret_cast<f16v8*>(hn + (size_t)(b * N_ + i) * C_ + g * CPG_) = H;
    }
}

// ---------------- 2. fused q/k/v projection ----------------
// q,k -> [b][n][c]; v -> vT [b][c][n] (swapped operands).
__global__ __launch_bounds__(256) void proj_qkv_kernel(
    const f16* __restrict__ hn, const f16* __restrict__ wq16,
    const f16* __restrict__ wk16, const f16* __restrict__ wv16,
    const float* __restrict__ bq, const float* __restrict__ bk,
    const float* __restrict__ bv,
    f16* __restrict__ qo, f16* __restrict__ ko, f16* __restrict__ vt)
{
    int it = blockIdx.x, b = blockIdx.y;
    int tid = threadIdx.x, w = tid >> 6, l = tid & 63;
    int l15 = l & 15, lhi = l >> 4;
    int i0 = it * 64 + w * 16;
    size_t arow = (size_t)(b * N_ + i0 + l15) * C_ + lhi * 8;
    f16v8 af[8];
    #pragma unroll
    for (int kk = 0; kk < 8; kk++) af[kk] = ldh(hn + arow + kk * 32);

    // q then k: D[i][oc]
    #pragma unroll
    for (int which = 0; which < 2; which++) {
        const f16* wgt = which ? wk16 : wq16;
        const float* bias = which ? bk : bq;
        f16* outp = which ? ko : qo;
        for (int oc = 0; oc < 16; oc++) {
            f32x4 acc = {0.f, 0.f, 0.f, 0.f};
            size_t wrow = (size_t)(oc * 16 + l15) * C_ + lhi * 8;
            #pragma unroll
            for (int kk = 0; kk < 8; kk++)
                acc = mfma16(af[kk], ldh(wgt + wrow + kk * 32), acc);
            float bia = bias[oc * 16 + l15];
            #pragma unroll
            for (int r = 0; r < 4; r++)
                outp[(size_t)(b * N_ + i0 + lhi * 4 + r) * C_ + oc * 16 + l15] =
                    (f16)(acc[r] + bia);
        }
    }
    // v: D[c_out][i] (weights as A-operand)
    for (int oc = 0; oc < 16; oc++) {
        f32x4 acc = {0.f, 0.f, 0.f, 0.f};
        size_t wrow = (size_t)(oc * 16 + l15) * C_ + lhi * 8;
        #pragma unroll
        for (int kk = 0; kk < 8; kk++)
            acc = mfma16(ldh(wv16 + wrow + kk * 32), af[kk], acc);
        #pragma unroll
        for (int r = 0; r < 4; r++) {
            int o = oc * 16 + lhi * 4 + r;
            vt[(size_t)(b * C_ + o) * N_ + i0 + l15] = (f16)(acc[r] + bv[o]);
        }
    }
}

// ---------------- 3. flash attention: swapped QK^T, dual global_load_lds ----
__device__ __forceinline__ void stage_k(const f16* kbase, f16* dst, int j0,
                                        int w, int l) {
    #pragma unroll
    for (int rd = 0; rd < 4; rd++) {
        int cb = (rd * 4 + w) * 64;          // wave-uniform chunk base
        int mc = cb + l;                     // this lane's 16B chunk
        int row = mc >> 5;                   // 32 chunks (512B) per row
        int xoff = ((mc & 31) << 4) ^ ((row & 7) << 4);
        const f16* gsrc = kbase + (size_t)(j0 + row) * C_ + (xoff >> 1);
        __builtin_amdgcn_global_load_lds(
            (const __attribute__((address_space(1))) void*)gsrc,
            (__attribute__((address_space(3))) void*)(dst + (size_t)cb * 8),
            16, 0, 0);
    }
}
// V tile: vT[b][c][j0..j0+31] -> linear LDS [256][32] (64B rows)
__device__ __forceinline__ void stage_v(const f16* vbase, f16* dst, int j0,
                                        int w, int l) {
    int tid = w * 64 + l;
    #pragma unroll
    for (int s = 0; s < 4; s++) {
        int cb = s * 256 + w * 64;           // wave-uniform chunk base
        const f16* gsrc = vbase + (size_t)(s * 64 + (tid >> 2)) * N_ + j0 + (tid & 3) * 8;
        __builtin_amdgcn_global_load_lds(
            (const __attribute__((address_space(1))) void*)gsrc,
            (__attribute__((address_space(3))) void*)(dst + (size_t)cb * 8),
            16, 0, 0);
    }
}

__global__ __launch_bounds__(256, 2) void flash_split_kernel(
    const f16* __restrict__ q, const f16* __restrict__ k,
    const f16* __restrict__ vT,
    f16* __restrict__ o0p, f16* __restrict__ o1p,
    float2* __restrict__ stats)
{
    // XCD-pinned: linear id % 8 -> XCD; group = (b,split), 2MB K/V L2-resident.
    int bi = blockIdx.x;
    int g = bi & 7;
    int it = bi >> 3;                 // 0..63
    int b = g >> 1, split = g & 1;
    int tid = threadIdx.x, w = tid >> 6, l = tid & 63;
    int l15 = l & 15, lhi = l >> 4;
    int i0 = it * 64 + w * 16;
    int jt0 = split * JT_PER;
    __shared__ __align__(16) f16 kb[2][32][256];     // 32 KB, XOR-swizzled
    __shared__ __align__(16) f16 vb[2][256][32];     // 32 KB, linear
    __shared__ __align__(16) unsigned int Plds[4][16][20];  // 5 KB

    const f16* kbase = k + (size_t)b * N_ * C_;
    const f16* vbase = vT + (size_t)b * C_ * N_;

    f16v8 qf[8];
    size_t qrow = (size_t)(b * N_ + i0 + l15) * C_ + lhi * 8;
    #pragma unroll
    for (int kk = 0; kk < 8; kk++) qf[kk] = ldh(q + qrow + kk * 32);

    // oacc[cc][r] = O^T[c = cc*16 + lhi*4 + r][i = i0 + l15]
    f32x4 oacc[16];
    #pragma unroll
    for (int cc = 0; cc < 16; cc++) oacc[cc] = (f32x4){0.f, 0.f, 0.f, 0.f};
    float m = -1e30f, rsum = 0.f;    // per-lane: row i = i0 + l15

    stage_k(kbase, &kb[0][0][0], jt0 * 32, w, l);
    stage_v(vbase, &vb[0][0][0], jt0 * 32, w, l);
    __syncthreads();

    for (int jt = 0; jt < JT_PER; jt++) {
        int cur = jt & 1;
        int j0 = (jt0 + jt) * 32;

        if (jt + 1 < JT_PER) {
            stage_k(kbase, &kb[cur ^ 1][0][0], j0 + 32, w, l);
            stage_v(vbase, &vb[cur ^ 1][0][0], j0 + 32, w, l);
        }

        // ---- swapped QK^T: s'[j][i] = mfma(K, Q) ----
        const char* kbc = (const char*)&kb[cur][0][0];
        f32x4 s0 = {0.f, 0.f, 0.f, 0.f};
        f32x4 s1 = {0.f, 0.f, 0.f, 0.f};
        #pragma unroll
        for (int kk = 0; kk < 8; kk++) {
            {
                int row = l15;
                int off = row * 512 + ((kk * 64 + lhi * 16) ^ ((row & 7) << 4));
                f16v8 kf = *reinterpret_cast<const f16v8*>(kbc + off);
                s0 = mfma16(kf, qf[kk], s0);
            }
            {
                int row = 16 + l15;
                int off = row * 512 + ((kk * 64 + lhi * 16) ^ ((row & 7) << 4));
                f16v8 kf = *reinterpret_cast<const f16v8*>(kbc + off);
                s1 = mfma16(kf, qf[kk], s1);
            }
        }

        // ---- per-lane online softmax with defer-max (THR=8) ----
        float mt = fmaxf(fmaxf(fmaxf(s0[0], s0[1]), fmaxf(s0[2], s0[3])),
                         fmaxf(fmaxf(s1[0], s1[1]), fmaxf(s1[2], s1[3])));
        mt = fmaxf(mt, __shfl_xor(mt, 16));
        mt = fmaxf(mt, __shfl_xor(mt, 32));
        if (!__all(mt <= m + 8.f)) {
            float mn = fmaxf(m, mt);
            float sc = __expf(m - mn);
            m = mn;
            rsum *= sc;
            #pragma unroll
            for (int cc = 0; cc < 16; cc++) {
                #pragma unroll
                for (int r = 0; r < 4; r++) oacc[cc][r] *= sc;
            }
        }
        float p0[4], p1[4];
        float ls = 0.f;
        #pragma unroll
        for (int r = 0; r < 4; r++) {
            p0[r] = __expf(s0[r] - m);
            p1[r] = __expf(s1[r] - m);
            ls += p0[r] + p1[r];
        }
        rsum += ls;

        // ---- P' -> LDS transposed (wave-local; lgkm-ordered, no barrier) ----
        uint2 pa = {pkh(p0[0], p0[1]), pkh(p0[2], p0[3])};
        uint2 pb = {pkh(p1[0], p1[1]), pkh(p1[2], p1[3])};
        *reinterpret_cast<uint2*>(&Plds[w][l15][lhi * 2])     = pa;
        *reinterpret_cast<uint2*>(&Plds[w][l15][8 + lhi * 2]) = pb;
        f16v8 pfB = *reinterpret_cast<const f16v8*>(&Plds[w][l15][lhi * 4]);

        // ---- O^T += V^T @ P' (V from linear LDS) ----
        const f16* vbc = &vb[cur][0][0];
        #pragma unroll
        for (int cc = 0; cc < 16; cc++) {
            f16v8 vf = *reinterpret_cast<const f16v8*>(vbc + (cc * 16 + l15) * 32 + lhi * 8);
            oacc[cc] = mfma16(vf, pfB, oacc[cc]);
        }

        __syncthreads();   // drains stage(jt+1) vmcnt; WAR guard for cur buffers
    }

    // final cross-lane lsum reduce (4 lanes share row i)
    rsum += __shfl_xor(rsum, 16);
    rsum += __shfl_xor(rsum, 32);
    float inv = 1.f / rsum;

    f16* op = split ? o1p : o0p;
    size_t obase = (size_t)(b * N_ + i0 + l15) * C_;
    #pragma unroll
    for (int cc = 0; cc < 16; cc++) {
        uint2 st = {pkh(oacc[cc][0] * inv, oacc[cc][1] * inv),
                    pkh(oacc[cc][2] * inv, oacc[cc][3] * inv)};
        *reinterpret_cast<uint2*>(op + obase + cc * 16 + lhi * 4) = st;
    }
    if (lhi == 0)
        stats[((size_t)split * B_ + b) * N_ + i0 + l15] = make_float2(m, rsum);
}

// ---------------- 4. fused combine + conv_o + bias + residual ----------------
__global__ __launch_bounds__(256) void final_kernel(
    const f16* __restrict__ o0p, const f16* __restrict__ o1p,
    const float2* __restrict__ stats, const f16* __restrict__ wo16,
    const float* __restrict__ bo, const float* __restrict__ x,
    float* __restrict__ out)
{
    int it = blockIdx.x, b = blockIdx.y;
    int tid = threadIdx.x, w = tid >> 6, l = tid & 63;
    int l15 = l & 15, lhi = l >> 4;
    int o0 = w * 64, i0 = it * 64;

    // per-row split weights (row = i0 + nc*16 + l15)
    f16 w0h[4], w1h[4];
    #pragma unroll
    for (int nc = 0; nc < 4; nc++) {
        int row = i0 + nc * 16 + l15;
        float2 s0 = stats[(size_t)b * N_ + row];
        float2 s1 = stats[((size_t)B_ + b) * N_ + row];
        float M = fmaxf(s0.x, s1.x);
        float a0 = s0.y * __expf(s0.x - M);
        float a1 = s1.y * __expf(s1.x - M);
        float inv = 1.f / (a0 + a1);
        w0h[nc] = (f16)(a0 * inv);
        w1h[nc] = (f16)(a1 * inv);
    }

    f32x4 acc[4][4];
    #pragma unroll
    for (int mc = 0; mc < 4; mc++)
        #pragma unroll
        for (int nc = 0; nc < 4; nc++) acc[mc][nc] = (f32x4){0.f, 0.f, 0.f, 0.f};
    for (int kk = 0; kk < 8; kk++) {
        f16v8 af[4], bfv[4];
        #pragma unroll
        for (int mc = 0; mc < 4; mc++)
            af[mc] = ldh(wo16 + (size_t)(o0 + mc * 16 + l15) * C_ + kk * 32 + lhi * 8);
        #pragma unroll
        for (int nc = 0; nc < 4; nc++) {
            size_t off = (size_t)(b * N_ + i0 + nc * 16 + l15) * C_ + kk * 32 + lhi * 8;
            f16v8 a = ldh(o0p + off);
            f16v8 c = ldh(o1p + off);
            bfv[nc] = a * w0h[nc] + c * w1h[nc];
        }
        #pragma unroll
        for (int mc = 0; mc < 4; mc++)
            #pragma unroll
            for (int nc = 0; nc < 4; nc++)
                acc[mc][nc] = mfma16(af[mc], bfv[nc], acc[mc][nc]);
    }
    #pragma unroll
    for (int mc = 0; mc < 4; mc++) {
        float bia[4];
        #pragma unroll
        for (int r = 0; r < 4; r++) bia[r] = bo[o0 + mc * 16 + lhi * 4 + r];
        #pragma unroll
        for (int nc = 0; nc < 4; nc++)
            #pragma unroll
            for (int r = 0; r < 4; r++) {
                int o = o0 + mc * 16 + lhi * 4 + r;
                int i = i0 + nc * 16 + l15;
                size_t idx = (size_t)(b * C_ + o) * N_ + i;
                out[idx] = x[idx] + acc[mc][nc][r] + bia[r];
            }
    }
}

extern "C" void kernel_launch(void* const* d_in, const int* in_sizes, int n_in,
                              void* d_out, int out_size, void* d_ws, size_t ws_size,
                              hipStream_t stream) {
    const float* x  = (const float*)d_in[0];
    const float* gg = (const float*)d_in[1];
    const float* gb = (const float*)d_in[2];
    const float* wq = (const float*)d_in[3];
    const float* bq = (const float*)d_in[4];
    const float* wk = (const float*)d_in[5];
    const float* bk = (const float*)d_in[6];
    const float* wv = (const float*)d_in[7];
    const float* bv = (const float*)d_in[8];
    const float* wo = (const float*)d_in[9];
    const float* bo = (const float*)d_in[10];
    float* out = (float*)d_out;

    char* p = (char*)d_ws;
    const size_t WSZ = (size_t)C_ * C_ * 2;       // 128 KB per fp16 weight
    const size_t HSZ = (size_t)B_ * N_ * C_ * 2;  // 8 MB per fp16 activation
    f16* wq16 = (f16*)p; p += WSZ;
    f16* wk16 = (f16*)p; p += WSZ;
    f16* wv16 = (f16*)p; p += WSZ;
    f16* wo16 = (f16*)p; p += WSZ;
    f16* hn   = (f16*)p; p += HSZ;
    f16* qo   = (f16*)p; p += HSZ;
    f16* ko   = (f16*)p; p += HSZ;
    f16* vt   = (f16*)p; p += HSZ;
    f16* o1p  = (f16*)p; p += HSZ;                // split-1 partial
    float2* stats = (float2*)p; p += (size_t)SPLITS * B_ * N_ * sizeof(float2);

    f16* o0p = hn;            // hn dead after projections; split-0 partial

    conv_w_kernel<<<dim3(C_ * C_ / 256), 256, 0, stream>>>(
        wq, wk, wv, wo, wq16, wk16, wv16, wo16);
    gn_kernel<<<dim3(B_ * NG_), 256, 0, stream>>>(x, gg, gb, hn);
    proj_qkv_kernel<<<dim3(N_ / 64, B_), 256, 0, stream>>>(
        hn, wq16, wk16, wv16, bq, bk, bv, qo, ko, vt);
    flash_split_kernel<<<dim3(N_ / 64 * B_ * SPLITS), 256, 0, stream>>>(
        qo, ko, vt, o0p, o1p, stats);
    final_kernel<<<dim3(N_ / 64, B_), 256, 0, stream>>>(
        o0p, o1p, stats, wo16, bo, x, out);
}